// Round 6
// baseline (797.517 us; speedup 1.0000x reference)
//
#include <hip/hip_runtime.h>
#include <math.h>

// SCQ layer forward.
//   dense+LN f32 (argmin-critical Z bits - bf16 here would flip ~100 assigns).
//   score: split-bf16 MFMA approx dists + per-row top-2; rows with gap < TAU
//   re-scored by a compacted f32 tile-GEMM (round-3 structure, row-gathered).
//   Newton-Schulz pairs fused (X' = 2X - X(SX)) -> 6 launches.
//   post-argmin GEMMs (P_sol, Zq) split-bf16 x3 MFMA.

#define M_ 32768
#define D_ 256
#define K_ 512
#define TAU 0.006f

typedef short bf16x8 __attribute__((ext_vector_type(8)));
typedef unsigned short u16x8 __attribute__((ext_vector_type(8)));
typedef float f32x4 __attribute__((ext_vector_type(4)));

#define LSTR 56   // LDS row stride (ushorts)

// split 16 consecutive f32 into bf16 hi/lo planes (truncation split)
__device__ inline void stage16(const float* __restrict__ g,
                               unsigned short* __restrict__ lh,
                               unsigned short* __restrict__ ll)
{
    unsigned short hi[16], lo[16];
#pragma unroll
    for (int q = 0; q < 4; ++q) {
        float4 v = ((const float4*)g)[q];
        float f[4] = {v.x, v.y, v.z, v.w};
#pragma unroll
        for (int e = 0; e < 4; ++e) {
            unsigned int u = __float_as_uint(f[e]);
            unsigned short h = (unsigned short)(u >> 16);
            float fh = __uint_as_float(((unsigned int)h) << 16);
            float r = f[e] - fh;
            unsigned short l = (unsigned short)(__float_as_uint(r) >> 16);
            hi[q*4+e] = h; lo[q*4+e] = l;
        }
    }
    *(u16x8*)lh       = *(u16x8*)hi;
    *(u16x8*)(lh + 8) = *(u16x8*)(hi + 8);
    *(u16x8*)ll       = *(u16x8*)lo;
    *(u16x8*)(ll + 8) = *(u16x8*)(lo + 8);
}

// ---- MFMA GEMM: Out(MxN) = A(MxKd) @ Bt^T, Bt is (N x Kd) row-major --------
// EPI: 2 = +Ainv[assign[row],col] (psol, N=512); 3 = Zq + loss partials (N=256)
template<int EPI>
__global__ __launch_bounds__(256)
void mfma_gemm(const float* __restrict__ A, const float* __restrict__ Bt,
               float* __restrict__ Out, int Kd, int N,
               const float* __restrict__ AinvM, const int* __restrict__ assign,
               const float* Zref, float* __restrict__ lossPart)
{
    __shared__ unsigned short sAh[128*LSTR], sAl[128*LSTR];
    __shared__ unsigned short sBh[128*LSTR], sBl[128*LSTR];
    __shared__ float red[256];
    const int tid = threadIdx.x;
    const int m0 = blockIdx.y * 128, n0 = blockIdx.x * 128;
    const int w = tid >> 6, lane = tid & 63;
    const int wr = (w & 1) * 64, wc = (w >> 1) * 64;
    const int cg = lane >> 4, cr = lane & 15;

    f32x4 acc[4][4];
    const f32x4 z4 = {0.f, 0.f, 0.f, 0.f};
#pragma unroll
    for (int i = 0; i < 4; ++i)
#pragma unroll
        for (int j = 0; j < 4; ++j) acc[i][j] = z4;

    const int sr = tid >> 1;
    const int sk = (tid & 1) * 16;
    const float* Ag = A  + (size_t)(m0 + sr) * Kd + sk;
    const float* Bg = Bt + (size_t)(n0 + sr) * Kd + sk;
    const int soff = sr * LSTR + sk;

    for (int kb = 0; kb < Kd; kb += 32) {
        stage16(Ag + kb, sAh + soff, sAl + soff);
        stage16(Bg + kb, sBh + soff, sBl + soff);
        __syncthreads();
        bf16x8 ah[4], al[4], bh[4], bl[4];
#pragma unroll
        for (int f = 0; f < 4; ++f) {
            const int ao = (wr + f*16 + cr) * LSTR + cg*8;
            ah[f] = *(const bf16x8*)&sAh[ao];
            al[f] = *(const bf16x8*)&sAl[ao];
            const int bo = (wc + f*16 + cr) * LSTR + cg*8;
            bh[f] = *(const bf16x8*)&sBh[bo];
            bl[f] = *(const bf16x8*)&sBl[bo];
        }
#pragma unroll
        for (int i = 0; i < 4; ++i)
#pragma unroll
            for (int j = 0; j < 4; ++j) {
                acc[i][j] = __builtin_amdgcn_mfma_f32_16x16x32_bf16(ah[i], bh[j], acc[i][j], 0, 0, 0);
                acc[i][j] = __builtin_amdgcn_mfma_f32_16x16x32_bf16(al[i], bh[j], acc[i][j], 0, 0, 0);
                acc[i][j] = __builtin_amdgcn_mfma_f32_16x16x32_bf16(ah[i], bl[j], acc[i][j], 0, 0, 0);
            }
        __syncthreads();
    }

    if (EPI == 2) {
#pragma unroll
        for (int i = 0; i < 4; ++i) {
#pragma unroll
            for (int q = 0; q < 4; ++q) {
                const int row = m0 + wr + i*16 + cg*4 + q;
                const int am = assign[row];
                const float* Arow = AinvM + (size_t)am * K_ + n0 + wc;
#pragma unroll
                for (int j = 0; j < 4; ++j)
                    Out[(size_t)row * N + n0 + wc + j*16 + cr] =
                        acc[i][j][q] + Arow[j*16 + cr];
            }
        }
    } else {
        float lsum = 0.f;
#pragma unroll
        for (int i = 0; i < 4; ++i) {
#pragma unroll
            for (int q = 0; q < 4; ++q) {
                const int row = m0 + wr + i*16 + cg*4 + q;
#pragma unroll
                for (int j = 0; j < 4; ++j) {
                    const int col = n0 + wc + j*16 + cr;
                    const float v = acc[i][j][q];
                    const float zv = Zref[(size_t)row * N + col];
                    const float d = v - zv;
                    lsum += d * d;
                    Out[(size_t)row * N + col] = v;
                }
            }
        }
        red[tid] = lsum;
        __syncthreads();
        for (int s = 128; s > 0; s >>= 1) {
            if (tid < s) red[tid] += red[tid + s];
            __syncthreads();
        }
        if (tid == 0) lossPart[blockIdx.y * gridDim.x + blockIdx.x] = red[0];
    }
}

// -------- score: split-bf16 MFMA dists + per-row per-stripe top-2 -----------
__global__ __launch_bounds__(256)
void score_mfma_argmin(const float* __restrict__ A, const float* __restrict__ Bt,
                       const float* __restrict__ cn2, const float* __restrict__ zn2,
                       float* __restrict__ PV, float* __restrict__ PB,
                       int* __restrict__ PI)
{
    __shared__ unsigned short sAh[128*LSTR], sAl[128*LSTR];
    __shared__ unsigned short sBh[128*LSTR], sBl[128*LSTR];
    __shared__ float l1v[128][2], l2v[128][2];
    __shared__ int   liv[128][2];
    const int tid = threadIdx.x;
    const int m0 = blockIdx.y * 128, n0 = blockIdx.x * 128;
    const int w = tid >> 6, lane = tid & 63;
    const int wr = (w & 1) * 64, wc = (w >> 1) * 64;
    const int cg = lane >> 4, cr = lane & 15;

    f32x4 acc[4][4];
    const f32x4 z4 = {0.f, 0.f, 0.f, 0.f};
#pragma unroll
    for (int i = 0; i < 4; ++i)
#pragma unroll
        for (int j = 0; j < 4; ++j) acc[i][j] = z4;

    const int sr = tid >> 1;
    const int sk = (tid & 1) * 16;
    const float* Ag = A  + (size_t)(m0 + sr) * D_ + sk;
    const float* Bg = Bt + (size_t)(n0 + sr) * D_ + sk;
    const int soff = sr * LSTR + sk;

    for (int kb = 0; kb < D_; kb += 32) {
        stage16(Ag + kb, sAh + soff, sAl + soff);
        stage16(Bg + kb, sBh + soff, sBl + soff);
        __syncthreads();
        bf16x8 ah[4], al[4], bh[4], bl[4];
#pragma unroll
        for (int f = 0; f < 4; ++f) {
            const int ao = (wr + f*16 + cr) * LSTR + cg*8;
            ah[f] = *(const bf16x8*)&sAh[ao];
            al[f] = *(const bf16x8*)&sAl[ao];
            const int bo = (wc + f*16 + cr) * LSTR + cg*8;
            bh[f] = *(const bf16x8*)&sBh[bo];
            bl[f] = *(const bf16x8*)&sBl[bo];
        }
#pragma unroll
        for (int i = 0; i < 4; ++i)
#pragma unroll
            for (int j = 0; j < 4; ++j) {
                acc[i][j] = __builtin_amdgcn_mfma_f32_16x16x32_bf16(ah[i], bh[j], acc[i][j], 0, 0, 0);
                acc[i][j] = __builtin_amdgcn_mfma_f32_16x16x32_bf16(al[i], bh[j], acc[i][j], 0, 0, 0);
                acc[i][j] = __builtin_amdgcn_mfma_f32_16x16x32_bf16(ah[i], bl[j], acc[i][j], 0, 0, 0);
            }
        __syncthreads();
    }

    const int half = wc >> 6;
#pragma unroll
    for (int i = 0; i < 4; ++i) {
#pragma unroll
        for (int q = 0; q < 4; ++q) {
            const int rl = wr + i*16 + cg*4 + q;
            const float zr = zn2[m0 + rl];
            float b1 = 3.4e38f, b2 = 3.4e38f; int i1 = 0x7fffffff;
#pragma unroll
            for (int j = 0; j < 4; ++j) {
                const int col = n0 + wc + j*16 + cr;
                const float d = (zr + cn2[col]) - 2.0f * acc[i][j][q];
                if (d < b1 || (d == b1 && col < i1)) { b2 = b1; b1 = d; i1 = col; }
                else if (d < b2) b2 = d;
            }
#pragma unroll
            for (int off = 1; off < 16; off <<= 1) {
                const float o1 = __shfl_xor(b1, off);
                const int   oi = __shfl_xor(i1, off);
                const float o2 = __shfl_xor(b2, off);
                if (o1 < b1 || (o1 == b1 && oi < i1)) { b2 = fminf(b1, o2); b1 = o1; i1 = oi; }
                else { b2 = fminf(o1, b2); }
            }
            if (cr == 0) { l1v[rl][half] = b1; l2v[rl][half] = b2; liv[rl][half] = i1; }
        }
    }
    __syncthreads();
    if (tid < 128) {
        const float a1 = l1v[tid][0], a2 = l2v[tid][0]; const int ai = liv[tid][0];
        const float c1 = l1v[tid][1], c2 = l2v[tid][1]; const int ci = liv[tid][1];
        float b1, b2; int bi;
        if (c1 < a1 || (c1 == a1 && ci < ai)) { b1 = c1; bi = ci; b2 = fminf(a1, c2); }
        else { b1 = a1; bi = ai; b2 = fminf(c1, a2); }
        const size_t o = (size_t)(m0 + tid) * 4 + blockIdx.x;
        PV[o] = b1; PB[o] = b2; PI[o] = bi;
    }
}

__global__ void argmin_reduce4(const float* __restrict__ PV, const float* __restrict__ PB,
                               const int* __restrict__ PI, int* __restrict__ assign,
                               int* __restrict__ rlist, int* __restrict__ rcount)
{
    const int m = blockIdx.x * 256 + threadIdx.x;
    float b1 = PV[(size_t)m*4], b2 = PB[(size_t)m*4]; int i1 = PI[(size_t)m*4];
#pragma unroll
    for (int s = 1; s < 4; ++s) {
        const float o1 = PV[(size_t)m*4+s], o2 = PB[(size_t)m*4+s];
        const int oi = PI[(size_t)m*4+s];
        if (o1 < b1 || (o1 == b1 && oi < i1)) { b2 = fminf(b1, o2); b1 = o1; i1 = oi; }
        else { b2 = fminf(o1, b2); }
    }
    assign[m] = i1;
    if (b2 - b1 < TAU) { const int p = atomicAdd(rcount, 1); rlist[p] = m; }
}

// -------- compacted f32 rescoring GEMM over ambiguous rows ------------------
// Round-3 f32 score+argmin structure; A rows gathered via rlist; B = C (D,K).
__global__ __launch_bounds__(256)
void repair_gemm(const float* __restrict__ Z, const float* __restrict__ B,
                 const float* __restrict__ cn2, const float* __restrict__ zn2,
                 const int* __restrict__ rlist, const int* __restrict__ rcount,
                 float* __restrict__ PV, int* __restrict__ PI)
{
    const int n = rcount[0];
    const int m0 = blockIdx.y * 128;
    if (m0 >= n) return;
    __shared__ float As[16][132];
    __shared__ float Bs[16][128];
    __shared__ int rows_s[128];
    const int tid = threadIdx.x;
    const int tx = tid & 15, ty = tid >> 4;
    const int n0 = blockIdx.x * 128;

    if (tid < 128) rows_s[tid] = (m0 + tid < n) ? rlist[m0 + tid] : rlist[0];
    __syncthreads();

    float acc[8][8];
#pragma unroll
    for (int i = 0; i < 8; ++i)
#pragma unroll
        for (int j = 0; j < 8; ++j) acc[i][j] = 0.f;

    const int ar = tid >> 1, ac = (tid & 1) * 8;
    const int br = tid >> 4, bc = (tid & 15) * 8;
    const float* Ap = Z + (size_t)rows_s[ar] * D_ + ac;
    const float* Bp = B + (size_t)br * K_ + n0 + bc;

    for (int kb = 0; kb < D_; kb += 16) {
        float4 a0 = *(const float4*)(Ap + kb);
        float4 a1 = *(const float4*)(Ap + kb + 4);
        float4 b0 = *(const float4*)(Bp + (size_t)kb * K_);
        float4 b1 = *(const float4*)(Bp + (size_t)kb * K_ + 4);
        As[ac+0][ar] = a0.x; As[ac+1][ar] = a0.y; As[ac+2][ar] = a0.z; As[ac+3][ar] = a0.w;
        As[ac+4][ar] = a1.x; As[ac+5][ar] = a1.y; As[ac+6][ar] = a1.z; As[ac+7][ar] = a1.w;
        *(float4*)&Bs[br][bc]     = b0;
        *(float4*)&Bs[br][bc + 4] = b1;
        __syncthreads();
#pragma unroll
        for (int kk = 0; kk < 16; ++kk) {
            float4 av0 = *(const float4*)&As[kk][ty*4];
            float4 av1 = *(const float4*)&As[kk][64 + ty*4];
            float4 bv0 = *(const float4*)&Bs[kk][tx*4];
            float4 bv1 = *(const float4*)&Bs[kk][64 + tx*4];
            float a_[8] = {av0.x, av0.y, av0.z, av0.w, av1.x, av1.y, av1.z, av1.w};
            float b_[8] = {bv0.x, bv0.y, bv0.z, bv0.w, bv1.x, bv1.y, bv1.z, bv1.w};
#pragma unroll
            for (int i = 0; i < 8; ++i)
#pragma unroll
                for (int j = 0; j < 8; ++j)
                    acc[i][j] = fmaf(a_[i], b_[j], acc[i][j]);
        }
        __syncthreads();
    }

    // per-row partial argmin over this 128-col stripe (shuffle over tx)
#pragma unroll
    for (int hi = 0; hi < 2; ++hi) {
#pragma unroll
        for (int i = 0; i < 4; ++i) {
            const int rl = hi*64 + ty*4 + i;
            if (m0 + rl >= n) continue;
            const float zr = zn2[rows_s[rl]];
            float best = 3.4e38f; int bi = 0x7fffffff;
#pragma unroll
            for (int hj = 0; hj < 2; ++hj) {
#pragma unroll
                for (int j = 0; j < 4; ++j) {
                    const int col = n0 + hj*64 + tx*4 + j;
                    const float t1 = zr + cn2[col];
                    const float d  = t1 - 2.0f * acc[hi*4+i][hj*4+j];
                    if (d < best) { best = d; bi = col; }
                }
            }
#pragma unroll
            for (int off = 1; off < 16; off <<= 1) {
                const float ov = __shfl_xor(best, off);
                const int   oi = __shfl_xor(bi, off);
                if (ov < best || (ov == best && oi < bi)) { best = ov; bi = oi; }
            }
            if (tx == 0) {
                PV[(size_t)(m0 + rl) * 4 + blockIdx.x] = best;
                PI[(size_t)(m0 + rl) * 4 + blockIdx.x] = bi;
            }
        }
    }
}

__global__ void repair_scatter(const float* __restrict__ PV, const int* __restrict__ PI,
                               const int* __restrict__ rlist, const int* __restrict__ rcount,
                               int* __restrict__ assign)
{
    const int r = blockIdx.x * 256 + threadIdx.x;
    if (r >= rcount[0]) return;
    float best = PV[(size_t)r * 4]; int bi = PI[(size_t)r * 4];
#pragma unroll
    for (int nb = 1; nb < 4; ++nb) {
        const float v = PV[(size_t)r * 4 + nb]; const int ix = PI[(size_t)r * 4 + nb];
        if (v < best || (v == best && ix < bi)) { best = v; bi = ix; }
    }
    assign[rlist[r]] = bi;
}

// ---------------- fused dense (64x256 tile, full width) + LayerNorm ----------
__global__ __launch_bounds__(256)
void dense_ln_kernel(const float* __restrict__ A, const float* __restrict__ Bw,
                     const float* __restrict__ bias, const float* __restrict__ gamma,
                     const float* __restrict__ beta, float* __restrict__ Z,
                     float* __restrict__ zn2)
{
    __shared__ float As[16][68];
    __shared__ float Bs[16][256];
    __shared__ float rred[64][17];
    __shared__ float rstat[64];
    const int tid = threadIdx.x, tx = tid & 15, ty = tid >> 4;
    const int m0 = blockIdx.x * 64;
    float acc[4][16];
#pragma unroll
    for (int i = 0; i < 4; ++i)
#pragma unroll
        for (int j = 0; j < 16; ++j) acc[i][j] = 0.f;

    const int ar = tid >> 2, ac = (tid & 3) * 4;
    const int br = tid >> 4, bc = (tid & 15) * 16;
    for (int kb = 0; kb < 256; kb += 16) {
        float4 a = *(const float4*)(A + (size_t)(m0 + ar) * 256 + kb + ac);
        As[ac+0][ar] = a.x; As[ac+1][ar] = a.y; As[ac+2][ar] = a.z; As[ac+3][ar] = a.w;
#pragma unroll
        for (int q = 0; q < 4; ++q)
            *(float4*)&Bs[br][bc + q*4] =
                *(const float4*)(Bw + (size_t)(kb + br) * 256 + bc + q*4);
        __syncthreads();
#pragma unroll
        for (int kk = 0; kk < 16; ++kk) {
            float4 a4 = *(const float4*)&As[kk][ty*4];
            float av[4] = {a4.x, a4.y, a4.z, a4.w};
            float bv[16];
#pragma unroll
            for (int q = 0; q < 4; ++q) {
                float4 b4 = *(const float4*)&Bs[kk][q*64 + tx*4];
                bv[q*4+0] = b4.x; bv[q*4+1] = b4.y; bv[q*4+2] = b4.z; bv[q*4+3] = b4.w;
            }
#pragma unroll
            for (int i = 0; i < 4; ++i)
#pragma unroll
                for (int j = 0; j < 16; ++j)
                    acc[i][j] = fmaf(av[i], bv[j], acc[i][j]);
        }
        __syncthreads();
    }

    float bcol[16];
#pragma unroll
    for (int q = 0; q < 4; ++q) {
        float4 b4 = *(const float4*)(bias + q*64 + tx*4);
        bcol[q*4+0] = b4.x; bcol[q*4+1] = b4.y; bcol[q*4+2] = b4.z; bcol[q*4+3] = b4.w;
    }
#pragma unroll
    for (int i = 0; i < 4; ++i)
#pragma unroll
        for (int j = 0; j < 16; ++j) acc[i][j] += bcol[j];

#pragma unroll
    for (int i = 0; i < 4; ++i) {
        float s = 0.f;
#pragma unroll
        for (int j = 0; j < 16; ++j) s += acc[i][j];
        rred[ty*4+i][tx] = s;
    }
    __syncthreads();
    if (tid < 64) {
        float s = 0.f;
#pragma unroll
        for (int t = 0; t < 16; ++t) s += rred[tid][t];
        rstat[tid] = s * (1.f / 256.f);
    }
    __syncthreads();
    float mean_[4];
#pragma unroll
    for (int i = 0; i < 4; ++i) mean_[i] = rstat[ty*4+i];

#pragma unroll
    for (int i = 0; i < 4; ++i) {
        float s = 0.f;
#pragma unroll
        for (int j = 0; j < 16; ++j) { float d = acc[i][j] - mean_[i]; s += d * d; }
        rred[ty*4+i][tx] = s;
    }
    __syncthreads();
    if (tid < 64) {
        float s = 0.f;
#pragma unroll
        for (int t = 0; t < 16; ++t) s += rred[tid][t];
        rstat[tid] = s * (1.f / 256.f);
    }
    __syncthreads();
    float rstd_[4];
#pragma unroll
    for (int i = 0; i < 4; ++i) rstd_[i] = sqrtf(rstat[ty*4+i] + 1e-5f);

    float gam[16], bet[16];
#pragma unroll
    for (int q = 0; q < 4; ++q) {
        float4 g4 = *(const float4*)(gamma + q*64 + tx*4);
        float4 e4 = *(const float4*)(beta  + q*64 + tx*4);
        gam[q*4+0] = g4.x; gam[q*4+1] = g4.y; gam[q*4+2] = g4.z; gam[q*4+3] = g4.w;
        bet[q*4+0] = e4.x; bet[q*4+1] = e4.y; bet[q*4+2] = e4.z; bet[q*4+3] = e4.w;
    }
#pragma unroll
    for (int i = 0; i < 4; ++i)
#pragma unroll
        for (int j = 0; j < 16; ++j) {
            const float d = acc[i][j] - mean_[i];
            acc[i][j] = gam[j] * (d / rstd_[i]) + bet[j];
        }

#pragma unroll
    for (int i = 0; i < 4; ++i) {
        float s = 0.f;
#pragma unroll
        for (int j = 0; j < 16; ++j) s += acc[i][j] * acc[i][j];
        rred[ty*4+i][tx] = s;
    }
    __syncthreads();
    if (tid < 64) {
        float s = 0.f;
#pragma unroll
        for (int t = 0; t < 16; ++t) s += rred[tid][t];
        zn2[m0 + tid] = s;
    }

#pragma unroll
    for (int i = 0; i < 4; ++i) {
        const int row = m0 + ty*4 + i;
#pragma unroll
        for (int q = 0; q < 4; ++q) {
            float4 v;
            v.x = acc[i][q*4+0]; v.y = acc[i][q*4+1];
            v.z = acc[i][q*4+2]; v.w = acc[i][q*4+3];
            *(float4*)(Z + (size_t)row * 256 + q*64 + tx*4) = v;
        }
    }
}

// ---------------- small GEMM: 64x64 tiles -----------------------------------
// TRA=0: A is (M,Kd).  TRA=1: A is (Kd,M) (Out = A^T B).  B is (Kd,N).
// EPI: 0 none; 2: I - acc; 3: acc + I; 4: diversity partials
template<int TRA, int EPI>
__global__ __launch_bounds__(256)
void small_gemm(const float* __restrict__ A, const float* __restrict__ B,
                const float* __restrict__ E, float* __restrict__ Out,
                int M, int N, int Kd,
                const float* __restrict__ cn2, float* __restrict__ divPart)
{
    __shared__ float As[16][68];
    __shared__ float Bs[16][68];
    __shared__ float red2[256];
    const int tid = threadIdx.x;
    const int tx = tid & 15, ty = tid >> 4;
    const int n0 = blockIdx.x * 64, m0 = blockIdx.y * 64;
    float acc[4][4];
#pragma unroll
    for (int i = 0; i < 4; ++i)
#pragma unroll
        for (int j = 0; j < 4; ++j) acc[i][j] = 0.f;

    for (int kb = 0; kb < Kd; kb += 16) {
        if (TRA == 0) {
            const int ar2 = tid >> 2, ac2 = (tid & 3) * 4;
            float4 a = *(const float4*)(A + (size_t)(m0 + ar2) * Kd + kb + ac2);
            As[ac2+0][ar2] = a.x; As[ac2+1][ar2] = a.y;
            As[ac2+2][ar2] = a.z; As[ac2+3][ar2] = a.w;
        } else {
            const int ar2 = tid >> 4, ac2 = (tid & 15) * 4;
            float4 a = *(const float4*)(A + (size_t)(kb + ar2) * M + m0 + ac2);
            *(float4*)&As[ar2][ac2] = a;
        }
        {
            const int br2 = tid >> 4, bc2 = (tid & 15) * 4;
            float4 b = *(const float4*)(B + (size_t)(kb + br2) * N + n0 + bc2);
            *(float4*)&Bs[br2][bc2] = b;
        }
        __syncthreads();
#pragma unroll
        for (int kk = 0; kk < 16; ++kk) {
            float4 a4 = *(const float4*)&As[kk][ty*4];
            float4 b4 = *(const float4*)&Bs[kk][tx*4];
            float a_[4] = {a4.x, a4.y, a4.z, a4.w};
            float b_[4] = {b4.x, b4.y, b4.z, b4.w};
#pragma unroll
            for (int i = 0; i < 4; ++i)
#pragma unroll
                for (int j = 0; j < 4; ++j)
                    acc[i][j] = fmaf(a_[i], b_[j], acc[i][j]);
        }
        __syncthreads();
    }
    if (EPI == 4) {
        float dsum = 0.f;
#pragma unroll
        for (int i = 0; i < 4; ++i) {
            const int row = m0 + ty*4 + i;
            const float ri = 1.f / sqrtf(fmaxf(cn2[row], 1e-12f));
#pragma unroll
            for (int j = 0; j < 4; ++j) {
                const int col = n0 + tx*4 + j;
                if (row != col) {
                    const float rj = 1.f / sqrtf(fmaxf(cn2[col], 1e-12f));
                    dsum += fmaxf(acc[i][j] * ri * rj, 0.f);
                }
            }
        }
        red2[tid] = dsum;
        __syncthreads();
        for (int s = 128; s > 0; s >>= 1) {
            if (tid < s) red2[tid] += red2[tid + s];
            __syncthreads();
        }
        if (tid == 0) divPart[blockIdx.y * gridDim.x + blockIdx.x] = red2[0];
        return;
    }
#pragma unroll
    for (int i = 0; i < 4; ++i) {
        const int row = m0 + ty*4 + i;
#pragma unroll
        for (int j = 0; j < 4; ++j) {
            const int col = n0 + tx*4 + j;
            float v = acc[i][j];
            if (EPI == 2) v = ((row == col) ? 1.f : 0.f) - v;
            else if (EPI == 3) v = v + ((row == col) ? 1.f : 0.f);
            Out[(size_t)row * N + col] = v;
        }
    }
}

// ---------- fused Newton-Schulz step: Xn = 2X - X*(S*X), 64x64 tiles --------
__global__ __launch_bounds__(256)
void ns_fused(const float* __restrict__ S, const float* __restrict__ X,
              float* __restrict__ Xn)
{
    __shared__ float Tp[256][68];   // T[:, j-panel] = S * X[:, j-panel]
    __shared__ float As[16][68];
    __shared__ float Bs[16][68];
    const int tid = threadIdx.x;
    const int tx = tid & 15, ty = tid >> 4;
    const int j0 = blockIdx.x * 64, i0 = blockIdx.y * 64;

    // stage 1: Tp = S * X[:, j0:j0+64] in four 64-row chunks
    for (int so = 0; so < 4; ++so) {
        float acc[4][4];
#pragma unroll
        for (int i = 0; i < 4; ++i)
#pragma unroll
            for (int j = 0; j < 4; ++j) acc[i][j] = 0.f;
        for (int kb = 0; kb < 256; kb += 16) {
            const int ar2 = tid >> 2, ac2 = (tid & 3) * 4;
            float4 a = *(const float4*)(S + (size_t)(so*64 + ar2) * 256 + kb + ac2);
            As[ac2+0][ar2] = a.x; As[ac2+1][ar2] = a.y;
            As[ac2+2][ar2] = a.z; As[ac2+3][ar2] = a.w;
            const int br2 = tid >> 4, bc2 = (tid & 15) * 4;
            *(float4*)&Bs[br2][bc2] = *(const float4*)(X + (size_t)(kb + br2) * 256 + j0 + bc2);
            __syncthreads();
#pragma unroll
            for (int kk = 0; kk < 16; ++kk) {
                float4 a4 = *(const float4*)&As[kk][ty*4];
                float4 b4 = *(const float4*)&Bs[kk][tx*4];
                float a_[4] = {a4.x, a4.y, a4.z, a4.w};
                float b_[4] = {b4.x, b4.y, b4.z, b4.w};
#pragma unroll
                for (int i = 0; i < 4; ++i)
#pragma unroll
                    for (int j = 0; j < 4; ++j)
                        acc[i][j] = fmaf(a_[i], b_[j], acc[i][j]);
            }
            __syncthreads();
        }
#pragma unroll
        for (int i = 0; i < 4; ++i)
#pragma unroll
            for (int j = 0; j < 4; ++j)
                Tp[so*64 + ty*4 + i][tx*4 + j] = acc[i][j];
        __syncthreads();
    }

    // stage 2: out = X[i0:i0+64, :] * Tp; Xn = 2X - out
    float acc2[4][4];
#pragma unroll
    for (int i = 0; i < 4; ++i)
#pragma unroll
        for (int j = 0; j < 4; ++j) acc2[i][j] = 0.f;
    for (int kb = 0; kb < 256; kb += 16) {
        const int ar2 = tid >> 2, ac2 = (tid & 3) * 4;
        float4 a = *(const float4*)(X + (size_t)(i0 + ar2) * 256 + kb + ac2);
        As[ac2+0][ar2] = a.x; As[ac2+1][ar2] = a.y;
        As[ac2+2][ar2] = a.z; As[ac2+3][ar2] = a.w;
        __syncthreads();
#pragma unroll
        for (int kk = 0; kk < 16; ++kk) {
            float4 a4 = *(const float4*)&As[kk][ty*4];
            float a_[4] = {a4.x, a4.y, a4.z, a4.w};
            float b_[4] = {Tp[kb+kk][tx*4+0], Tp[kb+kk][tx*4+1],
                           Tp[kb+kk][tx*4+2], Tp[kb+kk][tx*4+3]};
#pragma unroll
            for (int i = 0; i < 4; ++i)
#pragma unroll
                for (int j = 0; j < 4; ++j)
                    acc2[i][j] = fmaf(a_[i], b_[j], acc2[i][j]);
        }
        __syncthreads();
    }
#pragma unroll
    for (int i = 0; i < 4; ++i) {
        const int row = i0 + ty*4 + i;
#pragma unroll
        for (int j = 0; j < 4; ++j) {
            const int col = j0 + tx*4 + j;
            Xn[(size_t)row * 256 + col] =
                2.f * X[(size_t)row * 256 + col] - acc2[i][j];
        }
    }
}

// ---------------- Ct = C^T ; column norms of C -------------------------------
__global__ void transpose_ct(const float* __restrict__ C, float* __restrict__ Ct)
{
    const int idx = blockIdx.x * 256 + threadIdx.x;
    const int k = idx >> 8, d = idx & 255;
    Ct[idx] = C[(size_t)d * K_ + k];
}

__global__ void cn2_kernel(const float* __restrict__ C, float* __restrict__ cn2)
{
    const int k = blockIdx.x * 256 + threadIdx.x;
    float s = 0.f;
    for (int d = 0; d < D_; ++d) { float c = C[(size_t)d * K_ + k]; s = fmaf(c, c, s); }
    cn2[k] = s;
}

// ------------- ||S||_inf (via symmetry: column sums) -> X0 = c*I -------------
__global__ void scal_init_kernel(const float* __restrict__ S, float* __restrict__ X)
{
    __shared__ float red[256];
    const int t = threadIdx.x;
    float s = 0.f;
    for (int q = 0; q < D_; ++q) s += fabsf(S[(size_t)q * D_ + t]);
    red[t] = s; __syncthreads();
    for (int sh = 128; sh > 0; sh >>= 1) {
        if (t < sh) red[t] = fmaxf(red[t], red[t + sh]);
        __syncthreads();
    }
    const float c = 2.f / (1.f + red[0]);
    for (int idx = t; idx < D_ * D_; idx += 256) {
        const int i = idx >> 8, j = idx & 255;
        X[idx] = (i == j) ? c : 0.f;
    }
}

// ---------------- simplex projection, Michelot, one wave per row -------------
__global__ __launch_bounds__(256)
void project_kernel(float* P)
{
    const int wave = threadIdx.x >> 6;
    const int lane = threadIdx.x & 63;
    const int row = blockIdx.x * 4 + wave;
    const size_t base = (size_t)row * K_ + lane;
    float v[8];
#pragma unroll
    for (int j = 0; j < 8; ++j) v[j] = P[base + j * 64];

    float s = 0.f;
#pragma unroll
    for (int j = 0; j < 8; ++j) s += v[j];
    for (int off = 32; off > 0; off >>= 1) s += __shfl_xor(s, off);

    float theta = (s - 1.f) * (1.f / 512.f);
    int cnt = K_;
    for (int it = 0; it < K_; ++it) {
        float ls = 0.f; int lc = 0;
#pragma unroll
        for (int j = 0; j < 8; ++j)
            if (v[j] > theta) { ls += v[j]; ++lc; }
        for (int off = 32; off > 0; off >>= 1) {
            ls += __shfl_xor(ls, off);
            lc += __shfl_xor(lc, off);
        }
        if (lc == cnt) break;
        theta = (ls - 1.f) / (float)lc;
        cnt = lc;
    }
#pragma unroll
    for (int j = 0; j < 8; ++j) P[base + j * 64] = fmaxf(v[j] - theta, 0.f);
}

// ---------------- column partial sums of P (for p_j) -------------------------
__global__ __launch_bounds__(512)
void colsum_kernel(const float* __restrict__ P, float* __restrict__ part)
{
    const int k = threadIdx.x;
    const int b = blockIdx.x;
    float s = 0.f;
    const size_t base = (size_t)b * 128 * K_ + k;
    for (int r = 0; r < 128; ++r) s += P[base + (size_t)r * K_];
    part[(size_t)b * K_ + k] = s;
}

// ---------------- finalize (slim): scalars only ------------------------------
#define BLOCK_REDUCE_512(val, result) \
    red[t] = (val); __syncthreads(); \
    for (int s_ = 256; s_ > 0; s_ >>= 1) { if (t < s_) red[t] += red[t + s_]; __syncthreads(); } \
    result = red[0]; __syncthreads();

__global__ __launch_bounds__(512)
void finalize_kernel(const float* __restrict__ part, const float* __restrict__ divPart,
                     const float* __restrict__ lossPart, float* __restrict__ out_scal)
{
    __shared__ float red[512];
    const int t = threadIdx.x;

    float praw = 0.f;
    for (int b = 0; b < 256; ++b) praw += part[b * K_ + t];
    const float pm = praw * (1.f / 32768.f);

    const float pj = fminf(fmaxf(pm, 1e-10f), 1.0f);
    float sp; BLOCK_REDUCE_512(pj, sp);
    const float pjn = pj / sp;
    float Hbits; BLOCK_REDUCE_512(-pjn * logf(pjn) / 0.69314718056f, Hbits);

    float spm; BLOCK_REDUCE_512(pm, spm);
    const float s2 = spm + 1e-5f;
    const float pmn = pm / s2;
    float ereg; BLOCK_REDUCE_512(-pmn * logf(pmn + 1e-5f), ereg);

    float dv = (t < 64) ? divPart[t] : 0.f;
    float divs; BLOCK_REDUCE_512(dv, divs);
    const float divloss = divs * (1.f / 262144.f);

    float lp = lossPart[t];
    float prim; BLOCK_REDUCE_512(lp, prim);
    prim *= 1.f / 8388608.f;

    if (t == 0) {
        out_scal[0] = prim + 0.5f * ereg + 0.5f * divloss;
        out_scal[1] = exp2f(Hbits);
    }
}

// ---------------- launch -----------------------------------------------------
extern "C" void kernel_launch(void* const* d_in, const int* in_sizes, int n_in,
                              void* d_out, int out_size, void* d_ws, size_t ws_size,
                              hipStream_t stream)
{
    const float* inputs = (const float*)d_in[0];
    const float* gamma  = (const float*)d_in[1];
    const float* beta   = (const float*)d_in[2];
    const float* C      = (const float*)d_in[3];   // (D,K)
    const float* d_w    = (const float*)d_in[4];   // (D,D)
    const float* d_b    = (const float*)d_in[5];   // (D,)

    float* out = (float*)d_out;
    float* Z = out;                                 // M*D slot (Z, later Zq)
    float* P = out + (size_t)M_ * D_;               // M*K slot (P_sol -> P_proj)
    float* out_scal = P + (size_t)M_ * K_;          // loss, perplexity

    float* w = (float*)d_ws;
    float* Smat = w;     w += D_ * D_;
    float* Xa   = w;     w += D_ * D_;
    float* Xb   = w;     w += D_ * D_;
    float* Ut   = w;     w += K_ * D_;              // C^T Sinv  (512x256)
    float* Ainv = w;     w += K_ * K_;
    float* Ct   = w;     w += K_ * D_;
    float* cn2  = w;     w += K_;
    float* zn2  = w;     w += M_;
    float* part = w;     w += 256 * K_;
    float* lossPart = w; w += 512;
    float* divPart  = w; w += 64;
    float* PV   = w;     w += M_ * 4;
    float* PB   = w;     w += M_ * 4;
    int* PI     = (int*)w; w += M_ * 4;
    int* rlist  = (int*)w; w += M_;
    int* rcount = (int*)w; w += 16;
    int* assign = (int*)w;

    hipMemsetAsync(rcount, 0, sizeof(int), stream);

    // 1. Z = LN(inputs @ d_w + d_b), zn2    (f32, argmin-critical)
    dense_ln_kernel<<<M_/64, 256, 0, stream>>>(inputs, d_w, d_b, gamma, beta, Z, zn2);
    // 2. C^T and column norms
    transpose_ct<<<(K_ * D_) / 256, 256, 0, stream>>>(C, Ct);
    cn2_kernel<<<K_ / 256, 256, 0, stream>>>(C, cn2);
    // 3. S = C C^T + I
    small_gemm<1, 3><<<dim3(D_/64, D_/64), 256, 0, stream>>>(Ct, Ct, nullptr, Smat, D_, D_, K_, nullptr, nullptr);
    // 4. NS init
    scal_init_kernel<<<1, 256, 0, stream>>>(Smat, Xa);
    // 5. Newton-Schulz x6 (fused pairs): X <- 2X - X S X
    float* Xc = Xa; float* Xn = Xb;
    for (int it = 0; it < 6; ++it) {
        ns_fused<<<dim3(4, 4), 256, 0, stream>>>(Smat, Xc, Xn);
        float* tmp = Xc; Xc = Xn; Xn = tmp;
    }
    // 6. Ut = C^T Sinv ; Ainv = I - Ut C ; diversity partials from C^T C
    small_gemm<1, 0><<<dim3(D_/64, K_/64), 256, 0, stream>>>(C, Xc, nullptr, Ut, K_, D_, D_, nullptr, nullptr);
    small_gemm<0, 2><<<dim3(K_/64, K_/64), 256, 0, stream>>>(Ut, C, nullptr, Ainv, K_, K_, D_, nullptr, nullptr);
    small_gemm<1, 4><<<dim3(K_/64, K_/64), 256, 0, stream>>>(C, C, nullptr, nullptr, K_, K_, D_, cn2, divPart);
    // 7. approx dists (split-bf16 MFMA) + top-2 -> provisional assign + repair
    score_mfma_argmin<<<dim3(K_/128, M_/128), 256, 0, stream>>>(Z, Ct, cn2, zn2, PV, PB, PI);
    argmin_reduce4<<<M_/256, 256, 0, stream>>>(PV, PB, PI, assign, rlist, rcount);
    repair_gemm<<<dim3(K_/128, M_/128), 256, 0, stream>>>(Z, C, cn2, zn2, rlist, rcount, PV, PI);
    repair_scatter<<<M_/256, 256, 0, stream>>>(PV, PI, rlist, rcount, assign);
    // 8. P_sol^T = Z @ Ut^T + Ainv[assign,:]   (split-bf16 MFMA)
    mfma_gemm<2><<<dim3(K_/128, M_/128), 256, 0, stream>>>(
        Z, Ut, P, D_, K_, Ainv, assign, nullptr, nullptr);
    // 9. simplex projection in place
    project_kernel<<<M_/4, 256, 0, stream>>>(P);
    // 10. column partial sums
    colsum_kernel<<<256, 512, 0, stream>>>(P, part);
    // 11. Zq = P @ C^T (split-bf16 MFMA; B^T = C), loss partials
    mfma_gemm<3><<<dim3(D_/128, M_/128), 256, 0, stream>>>(
        P, C, Z, K_, D_, nullptr, nullptr, Z, lossPart);
    // 12. scalars
    finalize_kernel<<<1, 512, 0, stream>>>(part, divPart, lossPart, out_scal);

    (void)in_sizes; (void)n_in; (void)out_size; (void)ws_size;
}

// Round 7
// 587.166 us; speedup vs baseline: 1.3582x; 1.3582x over previous
//
#include <hip/hip_runtime.h>
#include <math.h>

// SCQ layer forward.
//   dense+LN f32 (argmin-critical Z bits).
//   score: split-bf16 (hi/lo x3) MFMA approx dists + per-row top-2; rows with
//   gap < TAU re-scored by compacted f32 tile-GEMM (exact chain).
//   Newton-Schulz via 12 plain small_gemm launches (fused variants regressed).
//   post-argmin GEMMs (P_sol, Zq): SINGLE bf16 (RNE) MFMA - error ~1e-4,
//   ~40x under threshold; halves LDS, 1/3 the MFMA, lighter staging.

#define M_ 32768
#define D_ 256
#define K_ 512
#define TAU 0.006f

typedef short bf16x8 __attribute__((ext_vector_type(8)));
typedef unsigned short u16x8 __attribute__((ext_vector_type(8)));
typedef float f32x4 __attribute__((ext_vector_type(4)));

#define LSTR 56   // LDS row stride (ushorts)

// split 16 consecutive f32 into bf16 hi/lo planes (truncation split)
__device__ inline void stage16(const float* __restrict__ g,
                               unsigned short* __restrict__ lh,
                               unsigned short* __restrict__ ll)
{
    unsigned short hi[16], lo[16];
#pragma unroll
    for (int q = 0; q < 4; ++q) {
        float4 v = ((const float4*)g)[q];
        float f[4] = {v.x, v.y, v.z, v.w};
#pragma unroll
        for (int e = 0; e < 4; ++e) {
            unsigned int u = __float_as_uint(f[e]);
            unsigned short h = (unsigned short)(u >> 16);
            float fh = __uint_as_float(((unsigned int)h) << 16);
            float r = f[e] - fh;
            unsigned short l = (unsigned short)(__float_as_uint(r) >> 16);
            hi[q*4+e] = h; lo[q*4+e] = l;
        }
    }
    *(u16x8*)lh       = *(u16x8*)hi;
    *(u16x8*)(lh + 8) = *(u16x8*)(hi + 8);
    *(u16x8*)ll       = *(u16x8*)lo;
    *(u16x8*)(ll + 8) = *(u16x8*)(lo + 8);
}

// round-to-nearest-even bf16, single plane
__device__ inline void stage16r(const float* __restrict__ g,
                                unsigned short* __restrict__ lh)
{
    unsigned short hi[16];
#pragma unroll
    for (int q = 0; q < 4; ++q) {
        float4 v = ((const float4*)g)[q];
        float f[4] = {v.x, v.y, v.z, v.w};
#pragma unroll
        for (int e = 0; e < 4; ++e) {
            unsigned int u = __float_as_uint(f[e]);
            u += 0x7FFFu + ((u >> 16) & 1u);
            hi[q*4+e] = (unsigned short)(u >> 16);
        }
    }
    *(u16x8*)lh       = *(u16x8*)hi;
    *(u16x8*)(lh + 8) = *(u16x8*)(hi + 8);
}

// ---- MFMA GEMM (single bf16 RNE): Out = A(MxKd) @ Bt^T, Bt (N x Kd) --------
// EPI: 2 = +Ainv[assign[row],col] (psol, N=512); 3 = Zq + loss partials (N=256)
template<int EPI>
__global__ __launch_bounds__(256)
void mfma_gemm(const float* __restrict__ A, const float* __restrict__ Bt,
               float* __restrict__ Out, int Kd, int N,
               const float* __restrict__ AinvM, const int* __restrict__ assign,
               const float* Zref, float* __restrict__ lossPart)
{
    __shared__ unsigned short sA[128*LSTR];
    __shared__ unsigned short sB[128*LSTR];
    __shared__ float red[256];
    const int tid = threadIdx.x;
    const int m0 = blockIdx.y * 128, n0 = blockIdx.x * 128;
    const int w = tid >> 6, lane = tid & 63;
    const int wr = (w & 1) * 64, wc = (w >> 1) * 64;
    const int cg = lane >> 4, cr = lane & 15;

    f32x4 acc[4][4];
    const f32x4 z4 = {0.f, 0.f, 0.f, 0.f};
#pragma unroll
    for (int i = 0; i < 4; ++i)
#pragma unroll
        for (int j = 0; j < 4; ++j) acc[i][j] = z4;

    const int sr = tid >> 1;
    const int sk = (tid & 1) * 16;
    const float* Ag = A  + (size_t)(m0 + sr) * Kd + sk;
    const float* Bg = Bt + (size_t)(n0 + sr) * Kd + sk;
    const int soff = sr * LSTR + sk;

    for (int kb = 0; kb < Kd; kb += 32) {
        stage16r(Ag + kb, sA + soff);
        stage16r(Bg + kb, sB + soff);
        __syncthreads();
        bf16x8 ah[4], bh[4];
#pragma unroll
        for (int f = 0; f < 4; ++f) {
            ah[f] = *(const bf16x8*)&sA[(wr + f*16 + cr) * LSTR + cg*8];
            bh[f] = *(const bf16x8*)&sB[(wc + f*16 + cr) * LSTR + cg*8];
        }
#pragma unroll
        for (int i = 0; i < 4; ++i)
#pragma unroll
            for (int j = 0; j < 4; ++j)
                acc[i][j] = __builtin_amdgcn_mfma_f32_16x16x32_bf16(ah[i], bh[j], acc[i][j], 0, 0, 0);
        __syncthreads();
    }

    if (EPI == 2) {
#pragma unroll
        for (int i = 0; i < 4; ++i) {
#pragma unroll
            for (int q = 0; q < 4; ++q) {
                const int row = m0 + wr + i*16 + cg*4 + q;
                const int am = assign[row];
                const float* Arow = AinvM + (size_t)am * K_ + n0 + wc;
#pragma unroll
                for (int j = 0; j < 4; ++j)
                    Out[(size_t)row * N + n0 + wc + j*16 + cr] =
                        acc[i][j][q] + Arow[j*16 + cr];
            }
        }
    } else {
        float lsum = 0.f;
#pragma unroll
        for (int i = 0; i < 4; ++i) {
#pragma unroll
            for (int q = 0; q < 4; ++q) {
                const int row = m0 + wr + i*16 + cg*4 + q;
#pragma unroll
                for (int j = 0; j < 4; ++j) {
                    const int col = n0 + wc + j*16 + cr;
                    const float v = acc[i][j][q];
                    const float zv = Zref[(size_t)row * N + col];
                    const float d = v - zv;
                    lsum += d * d;
                    Out[(size_t)row * N + col] = v;
                }
            }
        }
        red[tid] = lsum;
        __syncthreads();
        for (int s = 128; s > 0; s >>= 1) {
            if (tid < s) red[tid] += red[tid + s];
            __syncthreads();
        }
        if (tid == 0) lossPart[blockIdx.y * gridDim.x + blockIdx.x] = red[0];
    }
}

// -------- score: split-bf16 x3 MFMA dists + per-row per-stripe top-2 --------
__global__ __launch_bounds__(256)
void score_mfma_argmin(const float* __restrict__ A, const float* __restrict__ Bt,
                       const float* __restrict__ cn2, const float* __restrict__ zn2,
                       float* __restrict__ PV, float* __restrict__ PB,
                       int* __restrict__ PI)
{
    __shared__ unsigned short sAh[128*LSTR], sAl[128*LSTR];
    __shared__ unsigned short sBh[128*LSTR], sBl[128*LSTR];
    __shared__ float l1v[128][2], l2v[128][2];
    __shared__ int   liv[128][2];
    const int tid = threadIdx.x;
    const int m0 = blockIdx.y * 128, n0 = blockIdx.x * 128;
    const int w = tid >> 6, lane = tid & 63;
    const int wr = (w & 1) * 64, wc = (w >> 1) * 64;
    const int cg = lane >> 4, cr = lane & 15;

    f32x4 acc[4][4];
    const f32x4 z4 = {0.f, 0.f, 0.f, 0.f};
#pragma unroll
    for (int i = 0; i < 4; ++i)
#pragma unroll
        for (int j = 0; j < 4; ++j) acc[i][j] = z4;

    const int sr = tid >> 1;
    const int sk = (tid & 1) * 16;
    const float* Ag = A  + (size_t)(m0 + sr) * D_ + sk;
    const float* Bg = Bt + (size_t)(n0 + sr) * D_ + sk;
    const int soff = sr * LSTR + sk;

    for (int kb = 0; kb < D_; kb += 32) {
        stage16(Ag + kb, sAh + soff, sAl + soff);
        stage16(Bg + kb, sBh + soff, sBl + soff);
        __syncthreads();
        bf16x8 ah[4], al[4], bh[4], bl[4];
#pragma unroll
        for (int f = 0; f < 4; ++f) {
            const int ao = (wr + f*16 + cr) * LSTR + cg*8;
            ah[f] = *(const bf16x8*)&sAh[ao];
            al[f] = *(const bf16x8*)&sAl[ao];
            const int bo = (wc + f*16 + cr) * LSTR + cg*8;
            bh[f] = *(const bf16x8*)&sBh[bo];
            bl[f] = *(const bf16x8*)&sBl[bo];
        }
#pragma unroll
        for (int i = 0; i < 4; ++i)
#pragma unroll
            for (int j = 0; j < 4; ++j) {
                acc[i][j] = __builtin_amdgcn_mfma_f32_16x16x32_bf16(ah[i], bh[j], acc[i][j], 0, 0, 0);
                acc[i][j] = __builtin_amdgcn_mfma_f32_16x16x32_bf16(al[i], bh[j], acc[i][j], 0, 0, 0);
                acc[i][j] = __builtin_amdgcn_mfma_f32_16x16x32_bf16(ah[i], bl[j], acc[i][j], 0, 0, 0);
            }
        __syncthreads();
    }

    const int half = wc >> 6;
#pragma unroll
    for (int i = 0; i < 4; ++i) {
#pragma unroll
        for (int q = 0; q < 4; ++q) {
            const int rl = wr + i*16 + cg*4 + q;
            const float zr = zn2[m0 + rl];
            float b1 = 3.4e38f, b2 = 3.4e38f; int i1 = 0x7fffffff;
#pragma unroll
            for (int j = 0; j < 4; ++j) {
                const int col = n0 + wc + j*16 + cr;
                const float d = (zr + cn2[col]) - 2.0f * acc[i][j][q];
                if (d < b1 || (d == b1 && col < i1)) { b2 = b1; b1 = d; i1 = col; }
                else if (d < b2) b2 = d;
            }
#pragma unroll
            for (int off = 1; off < 16; off <<= 1) {
                const float o1 = __shfl_xor(b1, off);
                const int   oi = __shfl_xor(i1, off);
                const float o2 = __shfl_xor(b2, off);
                if (o1 < b1 || (o1 == b1 && oi < i1)) { b2 = fminf(b1, o2); b1 = o1; i1 = oi; }
                else { b2 = fminf(o1, b2); }
            }
            if (cr == 0) { l1v[rl][half] = b1; l2v[rl][half] = b2; liv[rl][half] = i1; }
        }
    }
    __syncthreads();
    if (tid < 128) {
        const float a1 = l1v[tid][0], a2 = l2v[tid][0]; const int ai = liv[tid][0];
        const float c1 = l1v[tid][1], c2 = l2v[tid][1]; const int ci = liv[tid][1];
        float b1, b2; int bi;
        if (c1 < a1 || (c1 == a1 && ci < ai)) { b1 = c1; bi = ci; b2 = fminf(a1, c2); }
        else { b1 = a1; bi = ai; b2 = fminf(c1, a2); }
        const size_t o = (size_t)(m0 + tid) * 4 + blockIdx.x;
        PV[o] = b1; PB[o] = b2; PI[o] = bi;
    }
}

__global__ void argmin_reduce4(const float* __restrict__ PV, const float* __restrict__ PB,
                               const int* __restrict__ PI, int* __restrict__ assign,
                               int* __restrict__ rlist, int* __restrict__ rcount)
{
    const int m = blockIdx.x * 256 + threadIdx.x;
    float b1 = PV[(size_t)m*4], b2 = PB[(size_t)m*4]; int i1 = PI[(size_t)m*4];
#pragma unroll
    for (int s = 1; s < 4; ++s) {
        const float o1 = PV[(size_t)m*4+s], o2 = PB[(size_t)m*4+s];
        const int oi = PI[(size_t)m*4+s];
        if (o1 < b1 || (o1 == b1 && oi < i1)) { b2 = fminf(b1, o2); b1 = o1; i1 = oi; }
        else { b2 = fminf(o1, b2); }
    }
    assign[m] = i1;
    if (b2 - b1 < TAU) { const int p = atomicAdd(rcount, 1); rlist[p] = m; }
}

// -------- compacted f32 rescoring GEMM over ambiguous rows ------------------
__global__ __launch_bounds__(256)
void repair_gemm(const float* __restrict__ Z, const float* __restrict__ B,
                 const float* __restrict__ cn2, const float* __restrict__ zn2,
                 const int* __restrict__ rlist, const int* __restrict__ rcount,
                 float* __restrict__ PV, int* __restrict__ PI)
{
    const int n = rcount[0];
    const int m0 = blockIdx.y * 128;
    if (m0 >= n) return;
    __shared__ float As[16][132];
    __shared__ float Bs[16][128];
    __shared__ int rows_s[128];
    const int tid = threadIdx.x;
    const int tx = tid & 15, ty = tid >> 4;
    const int n0 = blockIdx.x * 128;

    if (tid < 128) rows_s[tid] = (m0 + tid < n) ? rlist[m0 + tid] : rlist[0];
    __syncthreads();

    float acc[8][8];
#pragma unroll
    for (int i = 0; i < 8; ++i)
#pragma unroll
        for (int j = 0; j < 8; ++j) acc[i][j] = 0.f;

    const int ar = tid >> 1, ac = (tid & 1) * 8;
    const int br = tid >> 4, bc = (tid & 15) * 8;
    const float* Ap = Z + (size_t)rows_s[ar] * D_ + ac;
    const float* Bp = B + (size_t)br * K_ + n0 + bc;

    for (int kb = 0; kb < D_; kb += 16) {
        float4 a0 = *(const float4*)(Ap + kb);
        float4 a1 = *(const float4*)(Ap + kb + 4);
        float4 b0 = *(const float4*)(Bp + (size_t)kb * K_);
        float4 b1 = *(const float4*)(Bp + (size_t)kb * K_ + 4);
        As[ac+0][ar] = a0.x; As[ac+1][ar] = a0.y; As[ac+2][ar] = a0.z; As[ac+3][ar] = a0.w;
        As[ac+4][ar] = a1.x; As[ac+5][ar] = a1.y; As[ac+6][ar] = a1.z; As[ac+7][ar] = a1.w;
        *(float4*)&Bs[br][bc]     = b0;
        *(float4*)&Bs[br][bc + 4] = b1;
        __syncthreads();
#pragma unroll
        for (int kk = 0; kk < 16; ++kk) {
            float4 av0 = *(const float4*)&As[kk][ty*4];
            float4 av1 = *(const float4*)&As[kk][64 + ty*4];
            float4 bv0 = *(const float4*)&Bs[kk][tx*4];
            float4 bv1 = *(const float4*)&Bs[kk][64 + tx*4];
            float a_[8] = {av0.x, av0.y, av0.z, av0.w, av1.x, av1.y, av1.z, av1.w};
            float b_[8] = {bv0.x, bv0.y, bv0.z, bv0.w, bv1.x, bv1.y, bv1.z, bv1.w};
#pragma unroll
            for (int i = 0; i < 8; ++i)
#pragma unroll
                for (int j = 0; j < 8; ++j)
                    acc[i][j] = fmaf(a_[i], b_[j], acc[i][j]);
        }
        __syncthreads();
    }

#pragma unroll
    for (int hi = 0; hi < 2; ++hi) {
#pragma unroll
        for (int i = 0; i < 4; ++i) {
            const int rl = hi*64 + ty*4 + i;
            if (m0 + rl >= n) continue;
            const float zr = zn2[rows_s[rl]];
            float best = 3.4e38f; int bi = 0x7fffffff;
#pragma unroll
            for (int hj = 0; hj < 2; ++hj) {
#pragma unroll
                for (int j = 0; j < 4; ++j) {
                    const int col = n0 + hj*64 + tx*4 + j;
                    const float t1 = zr + cn2[col];
                    const float d  = t1 - 2.0f * acc[hi*4+i][hj*4+j];
                    if (d < best) { best = d; bi = col; }
                }
            }
#pragma unroll
            for (int off = 1; off < 16; off <<= 1) {
                const float ov = __shfl_xor(best, off);
                const int   oi = __shfl_xor(bi, off);
                if (ov < best || (ov == best && oi < bi)) { best = ov; bi = oi; }
            }
            if (tx == 0) {
                PV[(size_t)(m0 + rl) * 4 + blockIdx.x] = best;
                PI[(size_t)(m0 + rl) * 4 + blockIdx.x] = bi;
            }
        }
    }
}

__global__ void repair_scatter(const float* __restrict__ PV, const int* __restrict__ PI,
                               const int* __restrict__ rlist, const int* __restrict__ rcount,
                               int* __restrict__ assign)
{
    const int r = blockIdx.x * 256 + threadIdx.x;
    if (r >= rcount[0]) return;
    float best = PV[(size_t)r * 4]; int bi = PI[(size_t)r * 4];
#pragma unroll
    for (int nb = 1; nb < 4; ++nb) {
        const float v = PV[(size_t)r * 4 + nb]; const int ix = PI[(size_t)r * 4 + nb];
        if (v < best || (v == best && ix < bi)) { best = v; bi = ix; }
    }
    assign[rlist[r]] = bi;
}

// ---------------- fused dense (64x256 tile, full width) + LayerNorm ----------
__global__ __launch_bounds__(256)
void dense_ln_kernel(const float* __restrict__ A, const float* __restrict__ Bw,
                     const float* __restrict__ bias, const float* __restrict__ gamma,
                     const float* __restrict__ beta, float* __restrict__ Z,
                     float* __restrict__ zn2)
{
    __shared__ float As[16][68];
    __shared__ float Bs[16][256];
    __shared__ float rred[64][17];
    __shared__ float rstat[64];
    const int tid = threadIdx.x, tx = tid & 15, ty = tid >> 4;
    const int m0 = blockIdx.x * 64;
    float acc[4][16];
#pragma unroll
    for (int i = 0; i < 4; ++i)
#pragma unroll
        for (int j = 0; j < 16; ++j) acc[i][j] = 0.f;

    const int ar = tid >> 2, ac = (tid & 3) * 4;
    const int br = tid >> 4, bc = (tid & 15) * 16;
    for (int kb = 0; kb < 256; kb += 16) {
        float4 a = *(const float4*)(A + (size_t)(m0 + ar) * 256 + kb + ac);
        As[ac+0][ar] = a.x; As[ac+1][ar] = a.y; As[ac+2][ar] = a.z; As[ac+3][ar] = a.w;
#pragma unroll
        for (int q = 0; q < 4; ++q)
            *(float4*)&Bs[br][bc + q*4] =
                *(const float4*)(Bw + (size_t)(kb + br) * 256 + bc + q*4);
        __syncthreads();
#pragma unroll
        for (int kk = 0; kk < 16; ++kk) {
            float4 a4 = *(const float4*)&As[kk][ty*4];
            float av[4] = {a4.x, a4.y, a4.z, a4.w};
            float bv[16];
#pragma unroll
            for (int q = 0; q < 4; ++q) {
                float4 b4 = *(const float4*)&Bs[kk][q*64 + tx*4];
                bv[q*4+0] = b4.x; bv[q*4+1] = b4.y; bv[q*4+2] = b4.z; bv[q*4+3] = b4.w;
            }
#pragma unroll
            for (int i = 0; i < 4; ++i)
#pragma unroll
                for (int j = 0; j < 16; ++j)
                    acc[i][j] = fmaf(av[i], bv[j], acc[i][j]);
        }
        __syncthreads();
    }

    float bcol[16];
#pragma unroll
    for (int q = 0; q < 4; ++q) {
        float4 b4 = *(const float4*)(bias + q*64 + tx*4);
        bcol[q*4+0] = b4.x; bcol[q*4+1] = b4.y; bcol[q*4+2] = b4.z; bcol[q*4+3] = b4.w;
    }
#pragma unroll
    for (int i = 0; i < 4; ++i)
#pragma unroll
        for (int j = 0; j < 16; ++j) acc[i][j] += bcol[j];

#pragma unroll
    for (int i = 0; i < 4; ++i) {
        float s = 0.f;
#pragma unroll
        for (int j = 0; j < 16; ++j) s += acc[i][j];
        rred[ty*4+i][tx] = s;
    }
    __syncthreads();
    if (tid < 64) {
        float s = 0.f;
#pragma unroll
        for (int t = 0; t < 16; ++t) s += rred[tid][t];
        rstat[tid] = s * (1.f / 256.f);
    }
    __syncthreads();
    float mean_[4];
#pragma unroll
    for (int i = 0; i < 4; ++i) mean_[i] = rstat[ty*4+i];

#pragma unroll
    for (int i = 0; i < 4; ++i) {
        float s = 0.f;
#pragma unroll
        for (int j = 0; j < 16; ++j) { float d = acc[i][j] - mean_[i]; s += d * d; }
        rred[ty*4+i][tx] = s;
    }
    __syncthreads();
    if (tid < 64) {
        float s = 0.f;
#pragma unroll
        for (int t = 0; t < 16; ++t) s += rred[tid][t];
        rstat[tid] = s * (1.f / 256.f);
    }
    __syncthreads();
    float rstd_[4];
#pragma unroll
    for (int i = 0; i < 4; ++i) rstd_[i] = sqrtf(rstat[ty*4+i] + 1e-5f);

    float gam[16], bet[16];
#pragma unroll
    for (int q = 0; q < 4; ++q) {
        float4 g4 = *(const float4*)(gamma + q*64 + tx*4);
        float4 e4 = *(const float4*)(beta  + q*64 + tx*4);
        gam[q*4+0] = g4.x; gam[q*4+1] = g4.y; gam[q*4+2] = g4.z; gam[q*4+3] = g4.w;
        bet[q*4+0] = e4.x; bet[q*4+1] = e4.y; bet[q*4+2] = e4.z; bet[q*4+3] = e4.w;
    }
#pragma unroll
    for (int i = 0; i < 4; ++i)
#pragma unroll
        for (int j = 0; j < 16; ++j) {
            const float d = acc[i][j] - mean_[i];
            acc[i][j] = gam[j] * (d / rstd_[i]) + bet[j];
        }

#pragma unroll
    for (int i = 0; i < 4; ++i) {
        float s = 0.f;
#pragma unroll
        for (int j = 0; j < 16; ++j) s += acc[i][j] * acc[i][j];
        rred[ty*4+i][tx] = s;
    }
    __syncthreads();
    if (tid < 64) {
        float s = 0.f;
#pragma unroll
        for (int t = 0; t < 16; ++t) s += rred[tid][t];
        zn2[m0 + tid] = s;
    }

#pragma unroll
    for (int i = 0; i < 4; ++i) {
        const int row = m0 + ty*4 + i;
#pragma unroll
        for (int q = 0; q < 4; ++q) {
            float4 v;
            v.x = acc[i][q*4+0]; v.y = acc[i][q*4+1];
            v.z = acc[i][q*4+2]; v.w = acc[i][q*4+3];
            *(float4*)(Z + (size_t)row * 256 + q*64 + tx*4) = v;
        }
    }
}

// ---------------- small GEMM: 64x64 tiles -----------------------------------
// TRA=0: A is (M,Kd).  TRA=1: A is (Kd,M) (Out = A^T B).  B is (Kd,N).
// EPI: 0 none; 1: 2*E - acc (NS); 2: I - acc; 3: acc + I; 4: diversity partials
template<int TRA, int EPI>
__global__ __launch_bounds__(256)
void small_gemm(const float* __restrict__ A, const float* __restrict__ B,
                const float* __restrict__ E, float* __restrict__ Out,
                int M, int N, int Kd,
                const float* __restrict__ cn2, float* __restrict__ divPart)
{
    __shared__ float As[16][68];
    __shared__ float Bs[16][68];
    __shared__ float red2[256];
    const int tid = threadIdx.x;
    const int tx = tid & 15, ty = tid >> 4;
    const int n0 = blockIdx.x * 64, m0 = blockIdx.y * 64;
    float acc[4][4];
#pragma unroll
    for (int i = 0; i < 4; ++i)
#pragma unroll
        for (int j = 0; j < 4; ++j) acc[i][j] = 0.f;

    for (int kb = 0; kb < Kd; kb += 16) {
        if (TRA == 0) {
            const int ar2 = tid >> 2, ac2 = (tid & 3) * 4;
            float4 a = *(const float4*)(A + (size_t)(m0 + ar2) * Kd + kb + ac2);
            As[ac2+0][ar2] = a.x; As[ac2+1][ar2] = a.y;
            As[ac2+2][ar2] = a.z; As[ac2+3][ar2] = a.w;
        } else {
            const int ar2 = tid >> 4, ac2 = (tid & 15) * 4;
            float4 a = *(const float4*)(A + (size_t)(kb + ar2) * M + m0 + ac2);
            *(float4*)&As[ar2][ac2] = a;
        }
        {
            const int br2 = tid >> 4, bc2 = (tid & 15) * 4;
            float4 b = *(const float4*)(B + (size_t)(kb + br2) * N + n0 + bc2);
            *(float4*)&Bs[br2][bc2] = b;
        }
        __syncthreads();
#pragma unroll
        for (int kk = 0; kk < 16; ++kk) {
            float4 a4 = *(const float4*)&As[kk][ty*4];
            float4 b4 = *(const float4*)&Bs[kk][tx*4];
            float a_[4] = {a4.x, a4.y, a4.z, a4.w};
            float b_[4] = {b4.x, b4.y, b4.z, b4.w};
#pragma unroll
            for (int i = 0; i < 4; ++i)
#pragma unroll
                for (int j = 0; j < 4; ++j)
                    acc[i][j] = fmaf(a_[i], b_[j], acc[i][j]);
        }
        __syncthreads();
    }
    if (EPI == 4) {
        float dsum = 0.f;
#pragma unroll
        for (int i = 0; i < 4; ++i) {
            const int row = m0 + ty*4 + i;
            const float ri = 1.f / sqrtf(fmaxf(cn2[row], 1e-12f));
#pragma unroll
            for (int j = 0; j < 4; ++j) {
                const int col = n0 + tx*4 + j;
                if (row != col) {
                    const float rj = 1.f / sqrtf(fmaxf(cn2[col], 1e-12f));
                    dsum += fmaxf(acc[i][j] * ri * rj, 0.f);
                }
            }
        }
        red2[tid] = dsum;
        __syncthreads();
        for (int s = 128; s > 0; s >>= 1) {
            if (tid < s) red2[tid] += red2[tid + s];
            __syncthreads();
        }
        if (tid == 0) divPart[blockIdx.y * gridDim.x + blockIdx.x] = red2[0];
        return;
    }
#pragma unroll
    for (int i = 0; i < 4; ++i) {
        const int row = m0 + ty*4 + i;
#pragma unroll
        for (int j = 0; j < 4; ++j) {
            const int col = n0 + tx*4 + j;
            float v = acc[i][j];
            if (EPI == 1) v = 2.f * E[(size_t)row * N + col] - v;
            else if (EPI == 2) v = ((row == col) ? 1.f : 0.f) - v;
            else if (EPI == 3) v = v + ((row == col) ? 1.f : 0.f);
            Out[(size_t)row * N + col] = v;
        }
    }
}

// ---------------- Ct = C^T ; column norms of C -------------------------------
__global__ void transpose_ct(const float* __restrict__ C, float* __restrict__ Ct)
{
    const int idx = blockIdx.x * 256 + threadIdx.x;
    const int k = idx >> 8, d = idx & 255;
    Ct[idx] = C[(size_t)d * K_ + k];
}

__global__ void cn2_kernel(const float* __restrict__ C, float* __restrict__ cn2)
{
    const int k = blockIdx.x * 256 + threadIdx.x;
    float s = 0.f;
    for (int d = 0; d < D_; ++d) { float c = C[(size_t)d * K_ + k]; s = fmaf(c, c, s); }
    cn2[k] = s;
}

// ------------- ||S||_inf (via symmetry: column sums) -> X0 = c*I -------------
__global__ void scal_init_kernel(const float* __restrict__ S, float* __restrict__ X)
{
    __shared__ float red[256];
    const int t = threadIdx.x;
    float s = 0.f;
    for (int q = 0; q < D_; ++q) s += fabsf(S[(size_t)q * D_ + t]);
    red[t] = s; __syncthreads();
    for (int sh = 128; sh > 0; sh >>= 1) {
        if (t < sh) red[t] = fmaxf(red[t], red[t + sh]);
        __syncthreads();
    }
    const float c = 2.f / (1.f + red[0]);
    for (int idx = t; idx < D_ * D_; idx += 256) {
        const int i = idx >> 8, j = idx & 255;
        X[idx] = (i == j) ? c : 0.f;
    }
}

// ---------------- simplex projection, Michelot, one wave per row -------------
__global__ __launch_bounds__(256)
void project_kernel(float* P)
{
    const int wave = threadIdx.x >> 6;
    const int lane = threadIdx.x & 63;
    const int row = blockIdx.x * 4 + wave;
    const size_t base = (size_t)row * K_ + lane;
    float v[8];
#pragma unroll
    for (int j = 0; j < 8; ++j) v[j] = P[base + j * 64];

    float s = 0.f;
#pragma unroll
    for (int j = 0; j < 8; ++j) s += v[j];
    for (int off = 32; off > 0; off >>= 1) s += __shfl_xor(s, off);

    float theta = (s - 1.f) * (1.f / 512.f);
    int cnt = K_;
    for (int it = 0; it < K_; ++it) {
        float ls = 0.f; int lc = 0;
#pragma unroll
        for (int j = 0; j < 8; ++j)
            if (v[j] > theta) { ls += v[j]; ++lc; }
        for (int off = 32; off > 0; off >>= 1) {
            ls += __shfl_xor(ls, off);
            lc += __shfl_xor(lc, off);
        }
        if (lc == cnt) break;
        theta = (ls - 1.f) / (float)lc;
        cnt = lc;
    }
#pragma unroll
    for (int j = 0; j < 8; ++j) P[base + j * 64] = fmaxf(v[j] - theta, 0.f);
}

// ---------------- column partial sums of P (for p_j) -------------------------
__global__ __launch_bounds__(512)
void colsum_kernel(const float* __restrict__ P, float* __restrict__ part)
{
    const int k = threadIdx.x;
    const int b = blockIdx.x;
    float s = 0.f;
    const size_t base = (size_t)b * 128 * K_ + k;
    for (int r = 0; r < 128; ++r) s += P[base + (size_t)r * K_];
    part[(size_t)b * K_ + k] = s;
}

// ---------------- finalize (slim): scalars only ------------------------------
#define BLOCK_REDUCE_512(val, result) \
    red[t] = (val); __syncthreads(); \
    for (int s_ = 256; s_ > 0; s_ >>= 1) { if (t < s_) red[t] += red[t + s_]; __syncthreads(); } \
    result = red[0]; __syncthreads();

__global__ __launch_bounds__(512)
void finalize_kernel(const float* __restrict__ part, const float* __restrict__ divPart,
                     const float* __restrict__ lossPart, float* __restrict__ out_scal)
{
    __shared__ float red[512];
    const int t = threadIdx.x;

    float praw = 0.f;
    for (int b = 0; b < 256; ++b) praw += part[b * K_ + t];
    const float pm = praw * (1.f / 32768.f);

    const float pj = fminf(fmaxf(pm, 1e-10f), 1.0f);
    float sp; BLOCK_REDUCE_512(pj, sp);
    const float pjn = pj / sp;
    float Hbits; BLOCK_REDUCE_512(-pjn * logf(pjn) / 0.69314718056f, Hbits);

    float spm; BLOCK_REDUCE_512(pm, spm);
    const float s2 = spm + 1e-5f;
    const float pmn = pm / s2;
    float ereg; BLOCK_REDUCE_512(-pmn * logf(pmn + 1e-5f), ereg);

    float dv = (t < 64) ? divPart[t] : 0.f;
    float divs; BLOCK_REDUCE_512(dv, divs);
    const float divloss = divs * (1.f / 262144.f);

    float lp = lossPart[t];
    float prim; BLOCK_REDUCE_512(lp, prim);
    prim *= 1.f / 8388608.f;

    if (t == 0) {
        out_scal[0] = prim + 0.5f * ereg + 0.5f * divloss;
        out_scal[1] = exp2f(Hbits);
    }
}

// ---------------- launch -----------------------------------------------------
extern "C" void kernel_launch(void* const* d_in, const int* in_sizes, int n_in,
                              void* d_out, int out_size, void* d_ws, size_t ws_size,
                              hipStream_t stream)
{
    const float* inputs = (const float*)d_in[0];
    const float* gamma  = (const float*)d_in[1];
    const float* beta   = (const float*)d_in[2];
    const float* C      = (const float*)d_in[3];   // (D,K)
    const float* d_w    = (const float*)d_in[4];   // (D,D)
    const float* d_b    = (const float*)d_in[5];   // (D,)

    float* out = (float*)d_out;
    float* Z = out;                                 // M*D slot (Z, later Zq)
    float* P = out + (size_t)M_ * D_;               // M*K slot (P_sol -> P_proj)
    float* out_scal = P + (size_t)M_ * K_;          // loss, perplexity

    float* w = (float*)d_ws;
    float* Smat = w;     w += D_ * D_;
    float* Xa   = w;     w += D_ * D_;
    float* Xb   = w;     w += D_ * D_;
    float* Tb   = w;     w += D_ * D_;
    float* Ut   = w;     w += K_ * D_;              // C^T Sinv  (512x256)
    float* Ainv = w;     w += K_ * K_;
    float* Ct   = w;     w += K_ * D_;
    float* cn2  = w;     w += K_;
    float* zn2  = w;     w += M_;
    float* part = w;     w += 256 * K_;
    float* lossPart = w; w += 512;
    float* divPart  = w; w += 64;
    float* PV   = w;     w += M_ * 4;
    float* PB   = w;     w += M_ * 4;
    int* PI     = (int*)w; w += M_ * 4;
    int* rlist  = (int*)w; w += M_;
    int* rcount = (int*)w; w += 16;
    int* assign = (int*)w;

    hipMemsetAsync(rcount, 0, sizeof(int), stream);

    // 1. Z = LN(inputs @ d_w + d_b), zn2    (f32, argmin-critical)
    dense_ln_kernel<<<M_/64, 256, 0, stream>>>(inputs, d_w, d_b, gamma, beta, Z, zn2);
    // 2. C^T and column norms
    transpose_ct<<<(K_ * D_) / 256, 256, 0, stream>>>(C, Ct);
    cn2_kernel<<<K_ / 256, 256, 0, stream>>>(C, cn2);
    // 3. S = C C^T + I
    small_gemm<1, 3><<<dim3(D_/64, D_/64), 256, 0, stream>>>(Ct, Ct, nullptr, Smat, D_, D_, K_, nullptr, nullptr);
    // 4. NS init
    scal_init_kernel<<<1, 256, 0, stream>>>(Smat, Xa);
    // 5. Newton-Schulz x6: X <- 2X - X S X  (plain pairs; fused variants lose)
    float* Xc = Xa; float* Xn = Xb;
    for (int it = 0; it < 6; ++it) {
        small_gemm<0, 0><<<dim3(D_/64, D_/64), 256, 0, stream>>>(Smat, Xc, nullptr, Tb, D_, D_, D_, nullptr, nullptr);
        small_gemm<0, 1><<<dim3(D_/64, D_/64), 256, 0, stream>>>(Xc, Tb, Xc, Xn, D_, D_, D_, nullptr, nullptr);
        float* tmp = Xc; Xc = Xn; Xn = tmp;
    }
    // 6. Ut = C^T Sinv ; Ainv = I - Ut C ; diversity partials from C^T C
    small_gemm<1, 0><<<dim3(D_/64, K_/64), 256, 0, stream>>>(C, Xc, nullptr, Ut, K_, D_, D_, nullptr, nullptr);
    small_gemm<0, 2><<<dim3(K_/64, K_/64), 256, 0, stream>>>(Ut, C, nullptr, Ainv, K_, K_, D_, nullptr, nullptr);
    small_gemm<1, 4><<<dim3(K_/64, K_/64), 256, 0, stream>>>(C, C, nullptr, nullptr, K_, K_, D_, cn2, divPart);
    // 7. approx dists (split-bf16 x3 MFMA) + top-2 -> assign + repair set
    score_mfma_argmin<<<dim3(K_/128, M_/128), 256, 0, stream>>>(Z, Ct, cn2, zn2, PV, PB, PI);
    argmin_reduce4<<<M_/256, 256, 0, stream>>>(PV, PB, PI, assign, rlist, rcount);
    repair_gemm<<<dim3(K_/128, M_/128), 256, 0, stream>>>(Z, C, cn2, zn2, rlist, rcount, PV, PI);
    repair_scatter<<<M_/256, 256, 0, stream>>>(PV, PI, rlist, rcount, assign);
    // 8. P_sol^T = Z @ Ut^T + Ainv[assign,:]   (single-bf16 MFMA)
    mfma_gemm<2><<<dim3(K_/128, M_/128), 256, 0, stream>>>(
        Z, Ut, P, D_, K_, Ainv, assign, nullptr, nullptr);
    // 9. simplex projection in place
    project_kernel<<<M_/4, 256, 0, stream>>>(P);
    // 10. column partial sums
    colsum_kernel<<<256, 512, 0, stream>>>(P, part);
    // 11. Zq = P @ C^T (single-bf16 MFMA; B^T = C), loss partials
    mfma_gemm<3><<<dim3(D_/128, M_/128), 256, 0, stream>>>(
        P, C, Z, K_, D_, nullptr, nullptr, Z, lossPart);
    // 12. scalars
    finalize_kernel<<<1, 512, 0, stream>>>(part, divPart, lossPart, out_scal);

    (void)in_sizes; (void)n_in; (void)out_size; (void)ws_size;
}

// Round 8
// 438.369 us; speedup vs baseline: 1.8193x; 1.3394x over previous
//
#include <hip/hip_runtime.h>
#include <math.h>

// SCQ layer forward.
//   dense+LN f32 (argmin-critical Z bits).
//   score: split-bf16 x3 MFMA + top-2; gap < TAU repaired by exact f32 GEMM.
//   small-matrix chain: split-K (grid.z=4) partial-buffer GEMMs, deterministic;
//   partial sums folded into consumer staging. NS x5 iterations.
//   post-argmin GEMMs (P_sol, Zq): single-bf16 RNE MFMA.

#define M_ 32768
#define D_ 256
#define K_ 512
#define TAU 0.006f

typedef short bf16x8 __attribute__((ext_vector_type(8)));
typedef unsigned short u16x8 __attribute__((ext_vector_type(8)));
typedef float f32x4 __attribute__((ext_vector_type(4)));

#define LSTR 56

// split 16 consecutive f32 into bf16 hi/lo planes (truncation split)
__device__ inline void stage16(const float* __restrict__ g,
                               unsigned short* __restrict__ lh,
                               unsigned short* __restrict__ ll)
{
    unsigned short hi[16], lo[16];
#pragma unroll
    for (int q = 0; q < 4; ++q) {
        float4 v = ((const float4*)g)[q];
        float f[4] = {v.x, v.y, v.z, v.w};
#pragma unroll
        for (int e = 0; e < 4; ++e) {
            unsigned int u = __float_as_uint(f[e]);
            unsigned short h = (unsigned short)(u >> 16);
            float fh = __uint_as_float(((unsigned int)h) << 16);
            float r = f[e] - fh;
            unsigned short l = (unsigned short)(__float_as_uint(r) >> 16);
            hi[q*4+e] = h; lo[q*4+e] = l;
        }
    }
    *(u16x8*)lh       = *(u16x8*)hi;
    *(u16x8*)(lh + 8) = *(u16x8*)(hi + 8);
    *(u16x8*)ll       = *(u16x8*)lo;
    *(u16x8*)(ll + 8) = *(u16x8*)(lo + 8);
}

// round-to-nearest-even bf16, single plane
__device__ inline void stage16r(const float* __restrict__ g,
                                unsigned short* __restrict__ lh)
{
    unsigned short hi[16];
#pragma unroll
    for (int q = 0; q < 4; ++q) {
        float4 v = ((const float4*)g)[q];
        float f[4] = {v.x, v.y, v.z, v.w};
#pragma unroll
        for (int e = 0; e < 4; ++e) {
            unsigned int u = __float_as_uint(f[e]);
            u += 0x7FFFu + ((u >> 16) & 1u);
            hi[q*4+e] = (unsigned short)(u >> 16);
        }
    }
    *(u16x8*)lh       = *(u16x8*)hi;
    *(u16x8*)(lh + 8) = *(u16x8*)(hi + 8);
}

// ---- MFMA GEMM (single bf16 RNE): Out = A(MxKd) @ Bt^T, Bt (N x Kd) --------
template<int EPI>
__global__ __launch_bounds__(256)
void mfma_gemm(const float* __restrict__ A, const float* __restrict__ Bt,
               float* __restrict__ Out, int Kd, int N,
               const float* __restrict__ AinvM, const int* __restrict__ assign,
               const float* Zref, float* __restrict__ lossPart)
{
    __shared__ unsigned short sA[128*LSTR];
    __shared__ unsigned short sB[128*LSTR];
    __shared__ float red[256];
    const int tid = threadIdx.x;
    const int m0 = blockIdx.y * 128, n0 = blockIdx.x * 128;
    const int w = tid >> 6, lane = tid & 63;
    const int wr = (w & 1) * 64, wc = (w >> 1) * 64;
    const int cg = lane >> 4, cr = lane & 15;

    f32x4 acc[4][4];
    const f32x4 z4 = {0.f, 0.f, 0.f, 0.f};
#pragma unroll
    for (int i = 0; i < 4; ++i)
#pragma unroll
        for (int j = 0; j < 4; ++j) acc[i][j] = z4;

    const int sr = tid >> 1;
    const int sk = (tid & 1) * 16;
    const float* Ag = A  + (size_t)(m0 + sr) * Kd + sk;
    const float* Bg = Bt + (size_t)(n0 + sr) * Kd + sk;
    const int soff = sr * LSTR + sk;

    for (int kb = 0; kb < Kd; kb += 32) {
        stage16r(Ag + kb, sA + soff);
        stage16r(Bg + kb, sB + soff);
        __syncthreads();
        bf16x8 ah[4], bh[4];
#pragma unroll
        for (int f = 0; f < 4; ++f) {
            ah[f] = *(const bf16x8*)&sA[(wr + f*16 + cr) * LSTR + cg*8];
            bh[f] = *(const bf16x8*)&sB[(wc + f*16 + cr) * LSTR + cg*8];
        }
#pragma unroll
        for (int i = 0; i < 4; ++i)
#pragma unroll
            for (int j = 0; j < 4; ++j)
                acc[i][j] = __builtin_amdgcn_mfma_f32_16x16x32_bf16(ah[i], bh[j], acc[i][j], 0, 0, 0);
        __syncthreads();
    }

    if (EPI == 2) {
#pragma unroll
        for (int i = 0; i < 4; ++i) {
#pragma unroll
            for (int q = 0; q < 4; ++q) {
                const int row = m0 + wr + i*16 + cg*4 + q;
                const int am = assign[row];
                const float* Arow = AinvM + (size_t)am * K_ + n0 + wc;
#pragma unroll
                for (int j = 0; j < 4; ++j)
                    Out[(size_t)row * N + n0 + wc + j*16 + cr] =
                        acc[i][j][q] + Arow[j*16 + cr];
            }
        }
    } else {
        float lsum = 0.f;
#pragma unroll
        for (int i = 0; i < 4; ++i) {
#pragma unroll
            for (int q = 0; q < 4; ++q) {
                const int row = m0 + wr + i*16 + cg*4 + q;
#pragma unroll
                for (int j = 0; j < 4; ++j) {
                    const int col = n0 + wc + j*16 + cr;
                    const float v = acc[i][j][q];
                    const float zv = Zref[(size_t)row * N + col];
                    const float d = v - zv;
                    lsum += d * d;
                    Out[(size_t)row * N + col] = v;
                }
            }
        }
        red[tid] = lsum;
        __syncthreads();
        for (int s = 128; s > 0; s >>= 1) {
            if (tid < s) red[tid] += red[tid + s];
            __syncthreads();
        }
        if (tid == 0) lossPart[blockIdx.y * gridDim.x + blockIdx.x] = red[0];
    }
}

// -------- score: split-bf16 x3 MFMA dists + per-row per-stripe top-2 --------
__global__ __launch_bounds__(256)
void score_mfma_argmin(const float* __restrict__ A, const float* __restrict__ Bt,
                       const float* __restrict__ cn2, const float* __restrict__ zn2,
                       float* __restrict__ PV, float* __restrict__ PB,
                       int* __restrict__ PI)
{
    __shared__ unsigned short sAh[128*LSTR], sAl[128*LSTR];
    __shared__ unsigned short sBh[128*LSTR], sBl[128*LSTR];
    __shared__ float l1v[128][2], l2v[128][2];
    __shared__ int   liv[128][2];
    const int tid = threadIdx.x;
    const int m0 = blockIdx.y * 128, n0 = blockIdx.x * 128;
    const int w = tid >> 6, lane = tid & 63;
    const int wr = (w & 1) * 64, wc = (w >> 1) * 64;
    const int cg = lane >> 4, cr = lane & 15;

    f32x4 acc[4][4];
    const f32x4 z4 = {0.f, 0.f, 0.f, 0.f};
#pragma unroll
    for (int i = 0; i < 4; ++i)
#pragma unroll
        for (int j = 0; j < 4; ++j) acc[i][j] = z4;

    const int sr = tid >> 1;
    const int sk = (tid & 1) * 16;
    const float* Ag = A  + (size_t)(m0 + sr) * D_ + sk;
    const float* Bg = Bt + (size_t)(n0 + sr) * D_ + sk;
    const int soff = sr * LSTR + sk;

    for (int kb = 0; kb < D_; kb += 32) {
        stage16(Ag + kb, sAh + soff, sAl + soff);
        stage16(Bg + kb, sBh + soff, sBl + soff);
        __syncthreads();
        bf16x8 ah[4], al[4], bh[4], bl[4];
#pragma unroll
        for (int f = 0; f < 4; ++f) {
            const int ao = (wr + f*16 + cr) * LSTR + cg*8;
            ah[f] = *(const bf16x8*)&sAh[ao];
            al[f] = *(const bf16x8*)&sAl[ao];
            const int bo = (wc + f*16 + cr) * LSTR + cg*8;
            bh[f] = *(const bf16x8*)&sBh[bo];
            bl[f] = *(const bf16x8*)&sBl[bo];
        }
#pragma unroll
        for (int i = 0; i < 4; ++i)
#pragma unroll
            for (int j = 0; j < 4; ++j) {
                acc[i][j] = __builtin_amdgcn_mfma_f32_16x16x32_bf16(ah[i], bh[j], acc[i][j], 0, 0, 0);
                acc[i][j] = __builtin_amdgcn_mfma_f32_16x16x32_bf16(al[i], bh[j], acc[i][j], 0, 0, 0);
                acc[i][j] = __builtin_amdgcn_mfma_f32_16x16x32_bf16(ah[i], bl[j], acc[i][j], 0, 0, 0);
            }
        __syncthreads();
    }

    const int half = wc >> 6;
#pragma unroll
    for (int i = 0; i < 4; ++i) {
#pragma unroll
        for (int q = 0; q < 4; ++q) {
            const int rl = wr + i*16 + cg*4 + q;
            const float zr = zn2[m0 + rl];
            float b1 = 3.4e38f, b2 = 3.4e38f; int i1 = 0x7fffffff;
#pragma unroll
            for (int j = 0; j < 4; ++j) {
                const int col = n0 + wc + j*16 + cr;
                const float d = (zr + cn2[col]) - 2.0f * acc[i][j][q];
                if (d < b1 || (d == b1 && col < i1)) { b2 = b1; b1 = d; i1 = col; }
                else if (d < b2) b2 = d;
            }
#pragma unroll
            for (int off = 1; off < 16; off <<= 1) {
                const float o1 = __shfl_xor(b1, off);
                const int   oi = __shfl_xor(i1, off);
                const float o2 = __shfl_xor(b2, off);
                if (o1 < b1 || (o1 == b1 && oi < i1)) { b2 = fminf(b1, o2); b1 = o1; i1 = oi; }
                else { b2 = fminf(o1, b2); }
            }
            if (cr == 0) { l1v[rl][half] = b1; l2v[rl][half] = b2; liv[rl][half] = i1; }
        }
    }
    __syncthreads();
    if (tid < 128) {
        const float a1 = l1v[tid][0], a2 = l2v[tid][0]; const int ai = liv[tid][0];
        const float c1 = l1v[tid][1], c2 = l2v[tid][1]; const int ci = liv[tid][1];
        float b1, b2; int bi;
        if (c1 < a1 || (c1 == a1 && ci < ai)) { b1 = c1; bi = ci; b2 = fminf(a1, c2); }
        else { b1 = a1; bi = ai; b2 = fminf(c1, a2); }
        const size_t o = (size_t)(m0 + tid) * 4 + blockIdx.x;
        PV[o] = b1; PB[o] = b2; PI[o] = bi;
    }
}

__global__ void argmin_reduce4(const float* __restrict__ PV, const float* __restrict__ PB,
                               const int* __restrict__ PI, int* __restrict__ assign,
                               int* __restrict__ rlist, int* __restrict__ rcount)
{
    const int m = blockIdx.x * 256 + threadIdx.x;
    float b1 = PV[(size_t)m*4], b2 = PB[(size_t)m*4]; int i1 = PI[(size_t)m*4];
#pragma unroll
    for (int s = 1; s < 4; ++s) {
        const float o1 = PV[(size_t)m*4+s], o2 = PB[(size_t)m*4+s];
        const int oi = PI[(size_t)m*4+s];
        if (o1 < b1 || (o1 == b1 && oi < i1)) { b2 = fminf(b1, o2); b1 = o1; i1 = oi; }
        else { b2 = fminf(o1, b2); }
    }
    assign[m] = i1;
    if (b2 - b1 < TAU) { const int p = atomicAdd(rcount, 1); rlist[p] = m; }
}

// -------- compacted f32 rescoring GEMM over ambiguous rows ------------------
__global__ __launch_bounds__(256)
void repair_gemm(const float* __restrict__ Z, const float* __restrict__ B,
                 const float* __restrict__ cn2, const float* __restrict__ zn2,
                 const int* __restrict__ rlist, const int* __restrict__ rcount,
                 float* __restrict__ PV, int* __restrict__ PI)
{
    const int n = rcount[0];
    const int m0 = blockIdx.y * 128;
    if (m0 >= n) return;
    __shared__ float As[16][132];
    __shared__ float Bs[16][128];
    __shared__ int rows_s[128];
    const int tid = threadIdx.x;
    const int tx = tid & 15, ty = tid >> 4;
    const int n0 = blockIdx.x * 128;

    if (tid < 128) rows_s[tid] = (m0 + tid < n) ? rlist[m0 + tid] : rlist[0];
    __syncthreads();

    float acc[8][8];
#pragma unroll
    for (int i = 0; i < 8; ++i)
#pragma unroll
        for (int j = 0; j < 8; ++j) acc[i][j] = 0.f;

    const int ar = tid >> 1, ac = (tid & 1) * 8;
    const int br = tid >> 4, bc = (tid & 15) * 8;
    const float* Ap = Z + (size_t)rows_s[ar] * D_ + ac;
    const float* Bp = B + (size_t)br * K_ + n0 + bc;

    for (int kb = 0; kb < D_; kb += 16) {
        float4 a0 = *(const float4*)(Ap + kb);
        float4 a1 = *(const float4*)(Ap + kb + 4);
        float4 b0 = *(const float4*)(Bp + (size_t)kb * K_);
        float4 b1 = *(const float4*)(Bp + (size_t)kb * K_ + 4);
        As[ac+0][ar] = a0.x; As[ac+1][ar] = a0.y; As[ac+2][ar] = a0.z; As[ac+3][ar] = a0.w;
        As[ac+4][ar] = a1.x; As[ac+5][ar] = a1.y; As[ac+6][ar] = a1.z; As[ac+7][ar] = a1.w;
        *(float4*)&Bs[br][bc]     = b0;
        *(float4*)&Bs[br][bc + 4] = b1;
        __syncthreads();
#pragma unroll
        for (int kk = 0; kk < 16; ++kk) {
            float4 av0 = *(const float4*)&As[kk][ty*4];
            float4 av1 = *(const float4*)&As[kk][64 + ty*4];
            float4 bv0 = *(const float4*)&Bs[kk][tx*4];
            float4 bv1 = *(const float4*)&Bs[kk][64 + tx*4];
            float a_[8] = {av0.x, av0.y, av0.z, av0.w, av1.x, av1.y, av1.z, av1.w};
            float b_[8] = {bv0.x, bv0.y, bv0.z, bv0.w, bv1.x, bv1.y, bv1.z, bv1.w};
#pragma unroll
            for (int i = 0; i < 8; ++i)
#pragma unroll
                for (int j = 0; j < 8; ++j)
                    acc[i][j] = fmaf(a_[i], b_[j], acc[i][j]);
        }
        __syncthreads();
    }

#pragma unroll
    for (int hi = 0; hi < 2; ++hi) {
#pragma unroll
        for (int i = 0; i < 4; ++i) {
            const int rl = hi*64 + ty*4 + i;
            if (m0 + rl >= n) continue;
            const float zr = zn2[rows_s[rl]];
            float best = 3.4e38f; int bi = 0x7fffffff;
#pragma unroll
            for (int hj = 0; hj < 2; ++hj) {
#pragma unroll
                for (int j = 0; j < 4; ++j) {
                    const int col = n0 + hj*64 + tx*4 + j;
                    const float t1 = zr + cn2[col];
                    const float d  = t1 - 2.0f * acc[hi*4+i][hj*4+j];
                    if (d < best) { best = d; bi = col; }
                }
            }
#pragma unroll
            for (int off = 1; off < 16; off <<= 1) {
                const float ov = __shfl_xor(best, off);
                const int   oi = __shfl_xor(bi, off);
                if (ov < best || (ov == best && oi < bi)) { best = ov; bi = oi; }
            }
            if (tx == 0) {
                PV[(size_t)(m0 + rl) * 4 + blockIdx.x] = best;
                PI[(size_t)(m0 + rl) * 4 + blockIdx.x] = bi;
            }
        }
    }
}

__global__ void repair_scatter(const float* __restrict__ PV, const int* __restrict__ PI,
                               const int* __restrict__ rlist, const int* __restrict__ rcount,
                               int* __restrict__ assign)
{
    const int r = blockIdx.x * 256 + threadIdx.x;
    if (r >= rcount[0]) return;
    float best = PV[(size_t)r * 4]; int bi = PI[(size_t)r * 4];
#pragma unroll
    for (int nb = 1; nb < 4; ++nb) {
        const float v = PV[(size_t)r * 4 + nb]; const int ix = PI[(size_t)r * 4 + nb];
        if (v < best || (v == best && ix < bi)) { best = v; bi = ix; }
    }
    assign[rlist[r]] = bi;
}

// ---------------- fused dense (64x256 tile) + LayerNorm ----------------------
__global__ __launch_bounds__(256)
void dense_ln_kernel(const float* __restrict__ A, const float* __restrict__ Bw,
                     const float* __restrict__ bias, const float* __restrict__ gamma,
                     const float* __restrict__ beta, float* __restrict__ Z,
                     float* __restrict__ zn2)
{
    __shared__ float As[16][68];
    __shared__ float Bs[16][256];
    __shared__ float rred[64][17];
    __shared__ float rstat[64];
    const int tid = threadIdx.x, tx = tid & 15, ty = tid >> 4;
    const int m0 = blockIdx.x * 64;
    float acc[4][16];
#pragma unroll
    for (int i = 0; i < 4; ++i)
#pragma unroll
        for (int j = 0; j < 16; ++j) acc[i][j] = 0.f;

    const int ar = tid >> 2, ac = (tid & 3) * 4;
    const int br = tid >> 4, bc = (tid & 15) * 16;
    for (int kb = 0; kb < 256; kb += 16) {
        float4 a = *(const float4*)(A + (size_t)(m0 + ar) * 256 + kb + ac);
        As[ac+0][ar] = a.x; As[ac+1][ar] = a.y; As[ac+2][ar] = a.z; As[ac+3][ar] = a.w;
#pragma unroll
        for (int q = 0; q < 4; ++q)
            *(float4*)&Bs[br][bc + q*4] =
                *(const float4*)(Bw + (size_t)(kb + br) * 256 + bc + q*4);
        __syncthreads();
#pragma unroll
        for (int kk = 0; kk < 16; ++kk) {
            float4 a4 = *(const float4*)&As[kk][ty*4];
            float av[4] = {a4.x, a4.y, a4.z, a4.w};
            float bv[16];
#pragma unroll
            for (int q = 0; q < 4; ++q) {
                float4 b4 = *(const float4*)&Bs[kk][q*64 + tx*4];
                bv[q*4+0] = b4.x; bv[q*4+1] = b4.y; bv[q*4+2] = b4.z; bv[q*4+3] = b4.w;
            }
#pragma unroll
            for (int i = 0; i < 4; ++i)
#pragma unroll
                for (int j = 0; j < 16; ++j)
                    acc[i][j] = fmaf(av[i], bv[j], acc[i][j]);
        }
        __syncthreads();
    }

    float bcol[16];
#pragma unroll
    for (int q = 0; q < 4; ++q) {
        float4 b4 = *(const float4*)(bias + q*64 + tx*4);
        bcol[q*4+0] = b4.x; bcol[q*4+1] = b4.y; bcol[q*4+2] = b4.z; bcol[q*4+3] = b4.w;
    }
#pragma unroll
    for (int i = 0; i < 4; ++i)
#pragma unroll
        for (int j = 0; j < 16; ++j) acc[i][j] += bcol[j];

#pragma unroll
    for (int i = 0; i < 4; ++i) {
        float s = 0.f;
#pragma unroll
        for (int j = 0; j < 16; ++j) s += acc[i][j];
        rred[ty*4+i][tx] = s;
    }
    __syncthreads();
    if (tid < 64) {
        float s = 0.f;
#pragma unroll
        for (int t = 0; t < 16; ++t) s += rred[tid][t];
        rstat[tid] = s * (1.f / 256.f);
    }
    __syncthreads();
    float mean_[4];
#pragma unroll
    for (int i = 0; i < 4; ++i) mean_[i] = rstat[ty*4+i];

#pragma unroll
    for (int i = 0; i < 4; ++i) {
        float s = 0.f;
#pragma unroll
        for (int j = 0; j < 16; ++j) { float d = acc[i][j] - mean_[i]; s += d * d; }
        rred[ty*4+i][tx] = s;
    }
    __syncthreads();
    if (tid < 64) {
        float s = 0.f;
#pragma unroll
        for (int t = 0; t < 16; ++t) s += rred[tid][t];
        rstat[tid] = s * (1.f / 256.f);
    }
    __syncthreads();
    float rstd_[4];
#pragma unroll
    for (int i = 0; i < 4; ++i) rstd_[i] = sqrtf(rstat[ty*4+i] + 1e-5f);

    float gam[16], bet[16];
#pragma unroll
    for (int q = 0; q < 4; ++q) {
        float4 g4 = *(const float4*)(gamma + q*64 + tx*4);
        float4 e4 = *(const float4*)(beta  + q*64 + tx*4);
        gam[q*4+0] = g4.x; gam[q*4+1] = g4.y; gam[q*4+2] = g4.z; gam[q*4+3] = g4.w;
        bet[q*4+0] = e4.x; bet[q*4+1] = e4.y; bet[q*4+2] = e4.z; bet[q*4+3] = e4.w;
    }
#pragma unroll
    for (int i = 0; i < 4; ++i)
#pragma unroll
        for (int j = 0; j < 16; ++j) {
            const float d = acc[i][j] - mean_[i];
            acc[i][j] = gam[j] * (d / rstd_[i]) + bet[j];
        }

#pragma unroll
    for (int i = 0; i < 4; ++i) {
        float s = 0.f;
#pragma unroll
        for (int j = 0; j < 16; ++j) s += acc[i][j] * acc[i][j];
        rred[ty*4+i][tx] = s;
    }
    __syncthreads();
    if (tid < 64) {
        float s = 0.f;
#pragma unroll
        for (int t = 0; t < 16; ++t) s += rred[tid][t];
        zn2[m0 + tid] = s;
    }

#pragma unroll
    for (int i = 0; i < 4; ++i) {
        const int row = m0 + ty*4 + i;
#pragma unroll
        for (int q = 0; q < 4; ++q) {
            float4 v;
            v.x = acc[i][q*4+0]; v.y = acc[i][q*4+1];
            v.z = acc[i][q*4+2]; v.w = acc[i][q*4+3];
            *(float4*)(Z + (size_t)row * 256 + q*64 + tx*4) = v;
        }
    }
}

// ---------------- split-K small GEMM: 64x64 tiles, grid.z = 4 slices --------
// TRA=0: A (M,Kd); TRA=1: A (Kd,M) -> Out = A^T B.  B (Kd,N).
// ASUM: 1 = A is sum of 4 partials (stride M*Kd); 2 = same + identity.
// BSUM: 1 = B is sum of 4 partials (stride Kd*N).
// Out: partial at blockIdx.z * M * N.
template<int TRA, int ASUM, int BSUM>
__global__ __launch_bounds__(256)
void sk_gemm(const float* __restrict__ A, const float* __restrict__ B,
             float* __restrict__ Out, int M, int N, int Kd)
{
    __shared__ float As[16][68];
    __shared__ float Bs[16][68];
    const int tid = threadIdx.x;
    const int tx = tid & 15, ty = tid >> 4;
    const int n0 = blockIdx.x * 64, m0 = blockIdx.y * 64;
    const int kw = Kd >> 2;
    const int kb0 = blockIdx.z * kw;
    const size_t aP = (size_t)M * Kd;
    const size_t bP = (size_t)Kd * N;
    float acc[4][4];
#pragma unroll
    for (int i = 0; i < 4; ++i)
#pragma unroll
        for (int j = 0; j < 4; ++j) acc[i][j] = 0.f;

    for (int kb = kb0; kb < kb0 + kw; kb += 16) {
        if (TRA == 0) {
            const int ar2 = tid >> 2, ac2 = (tid & 3) * 4;
            const size_t off = (size_t)(m0 + ar2) * Kd + kb + ac2;
            float4 a;
            if (ASUM) {
                float4 a0 = *(const float4*)(A + off);
                float4 a1 = *(const float4*)(A + aP + off);
                float4 a2 = *(const float4*)(A + 2*aP + off);
                float4 a3 = *(const float4*)(A + 3*aP + off);
                a.x = a0.x + a1.x + a2.x + a3.x;
                a.y = a0.y + a1.y + a2.y + a3.y;
                a.z = a0.z + a1.z + a2.z + a3.z;
                a.w = a0.w + a1.w + a2.w + a3.w;
                if (ASUM == 2) {
                    const int row = m0 + ar2, colb = kb + ac2;
                    if (row == colb)     a.x += 1.f;
                    if (row == colb + 1) a.y += 1.f;
                    if (row == colb + 2) a.z += 1.f;
                    if (row == colb + 3) a.w += 1.f;
                }
            } else {
                a = *(const float4*)(A + off);
            }
            As[ac2+0][ar2] = a.x; As[ac2+1][ar2] = a.y;
            As[ac2+2][ar2] = a.z; As[ac2+3][ar2] = a.w;
        } else {
            const int ar2 = tid >> 4, ac2 = (tid & 15) * 4;
            float4 a = *(const float4*)(A + (size_t)(kb + ar2) * M + m0 + ac2);
            *(float4*)&As[ar2][ac2] = a;
        }
        {
            const int br2 = tid >> 4, bc2 = (tid & 15) * 4;
            const size_t off = (size_t)(kb + br2) * N + n0 + bc2;
            float4 b;
            if (BSUM) {
                float4 b0 = *(const float4*)(B + off);
                float4 b1 = *(const float4*)(B + bP + off);
                float4 b2 = *(const float4*)(B + 2*bP + off);
                float4 b3 = *(const float4*)(B + 3*bP + off);
                b.x = b0.x + b1.x + b2.x + b3.x;
                b.y = b0.y + b1.y + b2.y + b3.y;
                b.z = b0.z + b1.z + b2.z + b3.z;
                b.w = b0.w + b1.w + b2.w + b3.w;
            } else {
                b = *(const float4*)(B + off);
            }
            *(float4*)&Bs[br2][bc2] = b;
        }
        __syncthreads();
#pragma unroll
        for (int kk = 0; kk < 16; ++kk) {
            float4 a4 = *(const float4*)&As[kk][ty*4];
            float4 b4 = *(const float4*)&Bs[kk][tx*4];
            float a_[4] = {a4.x, a4.y, a4.z, a4.w};
            float b_[4] = {b4.x, b4.y, b4.z, b4.w};
#pragma unroll
            for (int i = 0; i < 4; ++i)
#pragma unroll
                for (int j = 0; j < 4; ++j)
                    acc[i][j] = fmaf(a_[i], b_[j], acc[i][j]);
        }
        __syncthreads();
    }
    float* Op = Out + (size_t)blockIdx.z * M * N;
#pragma unroll
    for (int i = 0; i < 4; ++i)
#pragma unroll
        for (int j = 0; j < 4; ++j)
            Op[(size_t)(m0 + ty*4 + i) * N + n0 + tx*4 + j] = acc[i][j];
}

// ---------------- small reduce kernels --------------------------------------
__global__ void xn_reduce(const float* __restrict__ Xc, const float* __restrict__ Xp,
                          float* __restrict__ Xn)
{
    const int idx = blockIdx.x * 256 + threadIdx.x;
    const float s = Xp[idx] + Xp[65536 + idx] + Xp[131072 + idx] + Xp[196608 + idx];
    Xn[idx] = 2.f * Xc[idx] - s;
}

__global__ void ainv_reduce(const float* __restrict__ Ap, float* __restrict__ Ainv)
{
    const int idx = blockIdx.x * 256 + threadIdx.x;
    const int i = idx >> 9, j = idx & 511;
    const float s = Ap[idx] + Ap[262144 + idx] + Ap[524288 + idx] + Ap[786432 + idx];
    Ainv[idx] = ((i == j) ? 1.f : 0.f) - s;
}

__global__ void g_reduce(const float* __restrict__ Gp, const float* __restrict__ cn2,
                         float* __restrict__ divPart)
{
    __shared__ float red[256];
    __shared__ float rsn[512];
    const int t = threadIdx.x;
    rsn[t]       = 1.f / sqrtf(fmaxf(cn2[t], 1e-12f));
    rsn[t + 256] = 1.f / sqrtf(fmaxf(cn2[t + 256], 1e-12f));
    __syncthreads();
    float dsum = 0.f;
#pragma unroll
    for (int e = 0; e < 4; ++e) {
        const int idx = blockIdx.x * 1024 + e * 256 + t;
        const int i = idx >> 9, j = idx & 511;
        const float g = Gp[idx] + Gp[262144 + idx] + Gp[524288 + idx] + Gp[786432 + idx];
        if (i != j) dsum += fmaxf(g * rsn[i] * rsn[j], 0.f);
    }
    red[t] = dsum; __syncthreads();
    for (int s = 128; s > 0; s >>= 1) {
        if (t < s) red[t] += red[t + s];
        __syncthreads();
    }
    if (t == 0) divPart[blockIdx.x] = red[0];
}

// row abs-sums of S = sum4(Sp) + I  (one row per block)
__global__ void rowabs_kernel(const float* __restrict__ Sp, float* __restrict__ rowAbs)
{
    __shared__ float red[256];
    const int r = blockIdx.x, t = threadIdx.x;
    const int idx = r * 256 + t;
    float v = Sp[idx] + Sp[65536 + idx] + Sp[131072 + idx] + Sp[196608 + idx];
    if (r == t) v += 1.f;
    red[t] = fabsf(v); __syncthreads();
    for (int s = 128; s > 0; s >>= 1) {
        if (t < s) red[t] += red[t + s];
        __syncthreads();
    }
    if (t == 0) rowAbs[r] = red[0];
}

__global__ void x0_init(const float* __restrict__ rowAbs, float* __restrict__ X)
{
    __shared__ float red[256];
    const int t = threadIdx.x;
    red[t] = rowAbs[t]; __syncthreads();
    for (int s = 128; s > 0; s >>= 1) {
        if (t < s) red[t] = fmaxf(red[t], red[t + s]);
        __syncthreads();
    }
    const float c = 2.f / (1.f + red[0]);
    const int idx = blockIdx.x * 256 + t;
    const int i = idx >> 8, j = idx & 255;
    X[idx] = (i == j) ? c : 0.f;
}

// ---------------- Ct = C^T ; column norms of C -------------------------------
__global__ void transpose_ct(const float* __restrict__ C, float* __restrict__ Ct)
{
    const int idx = blockIdx.x * 256 + threadIdx.x;
    const int k = idx >> 8, d = idx & 255;
    Ct[idx] = C[(size_t)d * K_ + k];
}

__global__ void cn2_kernel(const float* __restrict__ C, float* __restrict__ cn2)
{
    const int k = blockIdx.x * 256 + threadIdx.x;
    float s = 0.f;
    for (int d = 0; d < D_; ++d) { float c = C[(size_t)d * K_ + k]; s = fmaf(c, c, s); }
    cn2[k] = s;
}

// ---------------- simplex projection, Michelot, one wave per row -------------
__global__ __launch_bounds__(256)
void project_kernel(float* P)
{
    const int wave = threadIdx.x >> 6;
    const int lane = threadIdx.x & 63;
    const int row = blockIdx.x * 4 + wave;
    const size_t base = (size_t)row * K_ + lane;
    float v[8];
#pragma unroll
    for (int j = 0; j < 8; ++j) v[j] = P[base + j * 64];

    float s = 0.f;
#pragma unroll
    for (int j = 0; j < 8; ++j) s += v[j];
    for (int off = 32; off > 0; off >>= 1) s += __shfl_xor(s, off);

    float theta = (s - 1.f) * (1.f / 512.f);
    int cnt = K_;
    for (int it = 0; it < K_; ++it) {
        float ls = 0.f; int lc = 0;
#pragma unroll
        for (int j = 0; j < 8; ++j)
            if (v[j] > theta) { ls += v[j]; ++lc; }
        for (int off = 32; off > 0; off >>= 1) {
            ls += __shfl_xor(ls, off);
            lc += __shfl_xor(lc, off);
        }
        if (lc == cnt) break;
        theta = (ls - 1.f) / (float)lc;
        cnt = lc;
    }
#pragma unroll
    for (int j = 0; j < 8; ++j) P[base + j * 64] = fmaxf(v[j] - theta, 0.f);
}

// ---------------- column partial sums of P (for p_j) -------------------------
__global__ __launch_bounds__(512)
void colsum_kernel(const float* __restrict__ P, float* __restrict__ part)
{
    const int k = threadIdx.x;
    const int b = blockIdx.x;
    float s = 0.f;
    const size_t base = (size_t)b * 128 * K_ + k;
    for (int r = 0; r < 128; ++r) s += P[base + (size_t)r * K_];
    part[(size_t)b * K_ + k] = s;
}

// ---------------- finalize: scalars only -------------------------------------
#define BLOCK_REDUCE_512(val, result) \
    red[t] = (val); __syncthreads(); \
    for (int s_ = 256; s_ > 0; s_ >>= 1) { if (t < s_) red[t] += red[t + s_]; __syncthreads(); } \
    result = red[0]; __syncthreads();

__global__ __launch_bounds__(512)
void finalize_kernel(const float* __restrict__ part, const float* __restrict__ divPart,
                     const float* __restrict__ lossPart, float* __restrict__ out_scal)
{
    __shared__ float red[512];
    const int t = threadIdx.x;

    float praw = 0.f;
    for (int b = 0; b < 256; ++b) praw += part[b * K_ + t];
    const float pm = praw * (1.f / 32768.f);

    const float pj = fminf(fmaxf(pm, 1e-10f), 1.0f);
    float sp; BLOCK_REDUCE_512(pj, sp);
    const float pjn = pj / sp;
    float Hbits; BLOCK_REDUCE_512(-pjn * logf(pjn) / 0.69314718056f, Hbits);

    float spm; BLOCK_REDUCE_512(pm, spm);
    const float s2 = spm + 1e-5f;
    const float pmn = pm / s2;
    float ereg; BLOCK_REDUCE_512(-pmn * logf(pmn + 1e-5f), ereg);

    float dv = (t < 256) ? divPart[t] : 0.f;
    float divs; BLOCK_REDUCE_512(dv, divs);
    const float divloss = divs * (1.f / 262144.f);

    float lp = lossPart[t];
    float prim; BLOCK_REDUCE_512(lp, prim);
    prim *= 1.f / 8388608.f;

    if (t == 0) {
        out_scal[0] = prim + 0.5f * ereg + 0.5f * divloss;
        out_scal[1] = exp2f(Hbits);
    }
}

// ---------------- launch -----------------------------------------------------
extern "C" void kernel_launch(void* const* d_in, const int* in_sizes, int n_in,
                              void* d_out, int out_size, void* d_ws, size_t ws_size,
                              hipStream_t stream)
{
    const float* inputs = (const float*)d_in[0];
    const float* gamma  = (const float*)d_in[1];
    const float* beta   = (const float*)d_in[2];
    const float* C      = (const float*)d_in[3];   // (D,K)
    const float* d_w    = (const float*)d_in[4];   // (D,D)
    const float* d_b    = (const float*)d_in[5];   // (D,)

    float* out = (float*)d_out;
    float* Z = out;
    float* P = out + (size_t)M_ * D_;
    float* out_scal = P + (size_t)M_ * K_;

    float* w = (float*)d_ws;
    float* Sp   = w;     w += 4 * 65536;            // S partials (256x256 x4)
    float* Tp   = w;     w += 4 * 65536;            // T partials
    float* Xp   = w;     w += 4 * 65536;            // Xn partials
    float* Up   = w;     w += 4 * 131072;           // Ut partials (512x256 x4)
    float* Ap   = w;     w += 4 * 262144;           // Ainv / G partials (512x512 x4)
    float* Xa   = w;     w += 65536;
    float* Xb   = w;     w += 65536;
    float* Ainv = w;     w += 262144;
    float* Ct   = w;     w += 131072;
    float* cn2  = w;     w += 512;
    float* rowAbs = w;   w += 256;
    float* zn2  = w;     w += M_;
    float* part = w;     w += 256 * K_;
    float* lossPart = w; w += 512;
    float* divPart  = w; w += 256;
    float* PV   = w;     w += M_ * 4;
    float* PB   = w;     w += M_ * 4;
    int* PI     = (int*)w; w += M_ * 4;
    int* rlist  = (int*)w; w += M_;
    int* rcount = (int*)w; w += 16;
    int* assign = (int*)w;

    hipMemsetAsync(rcount, 0, sizeof(int), stream);

    // 1. Z = LN(inputs @ d_w + d_b), zn2    (f32, argmin-critical)
    dense_ln_kernel<<<M_/64, 256, 0, stream>>>(inputs, d_w, d_b, gamma, beta, Z, zn2);
    // 2. C^T and column norms
    transpose_ct<<<(K_ * D_) / 256, 256, 0, stream>>>(C, Ct);
    cn2_kernel<<<K_ / 256, 256, 0, stream>>>(C, cn2);
    // 3. S partials = C C^T (split-K; +I folded at consumers)
    sk_gemm<1, 0, 0><<<dim3(4, 4, 4), 256, 0, stream>>>(Ct, Ct, Sp, 256, 256, 512);
    // 4. NS init: rowAbs -> X0 = c*I
    rowabs_kernel<<<256, 256, 0, stream>>>(Sp, rowAbs);
    x0_init<<<256, 256, 0, stream>>>(rowAbs, Xa);
    // 5. Newton-Schulz x5: X <- 2X - X (S X)   (all split-K)
    float* Xc = Xa; float* Xn = Xb;
    for (int it = 0; it < 5; ++it) {
        sk_gemm<0, 2, 0><<<dim3(4, 4, 4), 256, 0, stream>>>(Sp, Xc, Tp, 256, 256, 256);
        sk_gemm<0, 0, 1><<<dim3(4, 4, 4), 256, 0, stream>>>(Xc, Tp, Xp, 256, 256, 256);
        xn_reduce<<<256, 256, 0, stream>>>(Xc, Xp, Xn);
        float* tmp = Xc; Xc = Xn; Xn = tmp;
    }
    // 6. Ut partials = C^T Sinv ; Ainv = I - Ut C ; G -> diversity
    sk_gemm<1, 0, 0><<<dim3(4, 8, 4), 256, 0, stream>>>(C, Xc, Up, 512, 256, 256);
    sk_gemm<0, 1, 0><<<dim3(8, 8, 4), 256, 0, stream>>>(Up, C, Ap, 512, 512, 256);
    ainv_reduce<<<1024, 256, 0, stream>>>(Ap, Ainv);
    sk_gemm<1, 0, 0><<<dim3(8, 8, 4), 256, 0, stream>>>(C, C, Ap, 512, 512, 256);
    g_reduce<<<256, 256, 0, stream>>>(Ap, cn2, divPart);
    // 7. Ut full (sum of partials) needed row-major for mfma psol:
    //    mfma reads Ut as Bt (N x Kd) row-major -> build dense Ut once
    // (reuse Tp slot as dense Ut buffer: 512x256 = 131072 <= 4*65536)
    {
        // dense_ut[idx] = sum4(Up)
        // grid 512 blocks x 256 threads
        // implemented via xn-like reduce below
    }
    // dense Ut reduce
    {
        struct L { static __global__ void k(const float* Up, float* Ut) {
        } };
    }
    // (see ut_reduce kernel below)
    extern __global__ void ut_reduce(const float*, float*);
    ut_reduce<<<512, 256, 0, stream>>>(Up, Tp);
    // 8. approx dists (split-bf16 x3 MFMA) + top-2 -> assign + repair set
    score_mfma_argmin<<<dim3(K_/128, M_/128), 256, 0, stream>>>(Z, Ct, cn2, zn2, PV, PB, PI);
    argmin_reduce4<<<M_/256, 256, 0, stream>>>(PV, PB, PI, assign, rlist, rcount);
    repair_gemm<<<dim3(K_/128, M_/128), 256, 0, stream>>>(Z, C, cn2, zn2, rlist, rcount, PV, PI);
    repair_scatter<<<M_/256, 256, 0, stream>>>(PV, PI, rlist, rcount, assign);
    // 9. P_sol^T = Z @ Ut^T + Ainv[assign,:]   (single-bf16 MFMA; Bt = dense Ut in Tp)
    mfma_gemm<2><<<dim3(K_/128, M_/128), 256, 0, stream>>>(
        Z, Tp, P, D_, K_, Ainv, assign, nullptr, nullptr);
    // 10. simplex projection in place
    project_kernel<<<M_/4, 256, 0, stream>>>(P);
    // 11. column partial sums
    colsum_kernel<<<256, 512, 0, stream>>>(P, part);
    // 12. Zq = P @ C^T (single-bf16 MFMA; B^T = C), loss partials
    mfma_gemm<3><<<dim3(D_/128, M_/128), 256, 0, stream>>>(
        P, C, Z, K_, D_, nullptr, nullptr, Z, lossPart);
    // 13. scalars
    finalize_kernel<<<1, 512, 0, stream>>>(part, divPart, lossPart, out_scal);

    (void)in_sizes; (void)n_in; (void)out_size; (void)ws_size;
}

// dense Ut = sum of 4 partials (512x256)
__global__ void ut_reduce(const float* __restrict__ Up, float* __restrict__ Ut)
{
    const int idx = blockIdx.x * 256 + threadIdx.x;
    Ut[idx] = Up[idx] + Up[131072 + idx] + Up[262144 + idx] + Up[393216 + idx];
}